// Round 14
// baseline (126.568 us; speedup 1.0000x reference)
//
#include <hip/hip_runtime.h>

// ---------------------------------------------------------------------------
// LinearDepthWiseAttention, round 14: r13 (=r10 best, 114.0us) +
//   (1) cast_w kernel ELIMINATED: fused kernel reads wqkv f32 directly,
//       converts A-frags in-register with identical f2bf (bit-identical).
//   (2) kv MFMA accumulation split into 4 independent 4-deep chains
//       (kvA/kvB per mi) for MFMA latency ILP; merged before exp.
//   kv   = w_qkv[512:1536] @ net ; ek = exp(k)      (never hits HBM)
//   ctx[b,h] += ek_h @ v_h^T ; rowsums via all-ones B-frag MFMA
//   W2 = fold(w_out, ctx/sum) ; W3[b] = W2[b] @ w_q^T ; out = W3 @ net + b_out
// Workspace:
//   netT  [16][4096][256] bf16 @ 0          (33554432)
//   ctxp  [128][4][64][64] f32 @ 33554432   (8388608)
//   sump  [128][4][64]     f32 @ 41943040   (131072)
//   W2    [16][256][512]  bf16 @ 42074112   (4194304)
//   W3    [16][256][256]  bf16 @ 46268416   (2097152)
//   wqTb  [256][512]      bf16 @ 48365568   (262144)
// ---------------------------------------------------------------------------

typedef unsigned short u16;
typedef unsigned int u32;
typedef __attribute__((ext_vector_type(4))) u16 u16x4;
typedef __attribute__((ext_vector_type(4))) u32 u32x4;
typedef __attribute__((ext_vector_type(4))) float f32x4;
typedef __attribute__((ext_vector_type(8))) short bf16x8;

__device__ __forceinline__ u16 f2bf(float f) {
  union { float f; u32 u; } x; x.f = f;
  u32 r = x.u + 0x7fffu + ((x.u >> 16) & 1u);   // round-to-nearest-even
  return (u16)(r >> 16);
}

// async global->LDS, 16B per lane; LDS dest must be wave-uniform base + lane*16.
__device__ __forceinline__ void async16(const u16* g, u16* l) {
  __builtin_amdgcn_global_load_lds(
      (const __attribute__((address_space(1))) void*)g,
      (__attribute__((address_space(3))) void*)l, 16, 0, 0);
}

// ---------------- generic transpose+cast: in[b][R][C] f32 -> out[b][C][R] bf16 ----
__global__ __launch_bounds__(256) void transpose_cast_g(const float* __restrict__ in,
                                                        u16* __restrict__ out,
                                                        int R, int C) {
  __shared__ float t[64][65];
  const int b = blockIdx.z, r0 = blockIdx.y * 64, c0 = blockIdx.x * 64;
  const float* ip = in + (size_t)b * R * C;
  u16* op = out + (size_t)b * R * C;
  const int tid = threadIdx.x;
  const int col4 = (tid & 15) * 4, rr0 = tid >> 4;
#pragma unroll
  for (int i = 0; i < 4; ++i) {
    int r = rr0 + i * 16;
    f32x4 v = *(const f32x4*)(ip + (size_t)(r0 + r) * C + c0 + col4);
    t[r][col4 + 0] = v[0]; t[r][col4 + 1] = v[1];
    t[r][col4 + 2] = v[2]; t[r][col4 + 3] = v[3];
  }
  __syncthreads();
  const int cc4 = (tid & 15) * 4, nr0 = tid >> 4;
#pragma unroll
  for (int i = 0; i < 4; ++i) {
    int nr = nr0 + i * 16;
    u16x4 u;
    u[0] = f2bf(t[cc4 + 0][nr]); u[1] = f2bf(t[cc4 + 1][nr]);
    u[2] = f2bf(t[cc4 + 2][nr]); u[3] = f2bf(t[cc4 + 3][nr]);
    *(u16x4*)(op + (size_t)(c0 + nr) * R + r0 + cc4) = u;
  }
}

// ---------------- fused kv + ctx (32-n chunks, 48KB LDS, 1 barrier/chunk) ----
// 512 threads = 8 waves: wq = wid&3 (32-row quarter of 128 kv rows),
// wn = wid>>2 (16-n half of the 32-n chunk). Per chunk c (32 chunks):
//   [__syncthreads]  (drains stage(c) vmem + ekv(c-1)/ctx(c-2) ds ops)
//   [stage(c+1) -> Bs[p^1]]
//   [setprio; ctx(c-1) from ekv[p^1]; kv(c) from Bs[p], 4 acc chains]
//   [exp + cheap-RNE + write ekv[p]]
__global__ __launch_bounds__(512, 4) void kv_ctx_fused(
    const float* __restrict__ wqkv,  // [1536][256] f32 (k rows 512.., v 1024..)
    const u16* __restrict__ netT,    // [16][4096][256] bf16
    float* __restrict__ ctxp,        // [128][4][64][64]
    float* __restrict__ sump) {      // [128][4][64]
  __shared__ __align__(16) u16 Bs[2][8192];    // 32KB: [buf][32 n][256 c] swizzled
  __shared__ __align__(16) u16 ekL[2][2048];   // 8KB [buf][64 d][32 n] swizzled
  __shared__ __align__(16) u16 vL[2][2048];    // 8KB [buf][64 e][32 n] swizzled

  // XCD-aware decode: xcd = flat&7 hosts batches {2*xcd, 2*xcd+1} only.
  const int flat = blockIdx.x;
  const int xcd = flat & 7, inner = flat >> 3;
  const int b = 2 * xcd + (inner >> 5);
  const int h = (inner >> 2) & 7;
  const int s = inner & 3;

  const int tid = threadIdx.x, lane = tid & 63, wid = tid >> 6;
  const int wq = wid & 3, wn = wid >> 2;
  const int lr = lane & 15, lg = lane >> 4;
  const bool isK = (wq < 2);

  // ---- A-frags: read wqkv f32 directly, convert in-reg (replaces cast_w) ----
  // row r<64 -> k row 512 + h*64 + r ; r>=64 -> v row 1024 + h*64 + (r-64)
  bf16x8 af[2][8];
#pragma unroll
  for (int mi = 0; mi < 2; ++mi) {
    const int r = wq * 32 + mi * 16 + lr;                  // 0..127
    const int grow = (r < 64) ? 512 + h * 64 + r : 1024 + h * 64 + (r - 64);
    const float* wrow = wqkv + (size_t)grow * 256 + lg * 8;
#pragma unroll
    for (int kk = 0; kk < 8; ++kk) {
      f32x4 w0 = *(const f32x4*)(wrow + kk * 32);
      f32x4 w1 = *(const f32x4*)(wrow + kk * 32 + 4);
      bf16x8 a;
#pragma unroll
      for (int j = 0; j < 4; ++j) {
        ((u16*)&a)[j] = f2bf(w0[j]);
        ((u16*)&a)[j + 4] = f2bf(w1[j]);
      }
      af[mi][kk] = a;
    }
  }

  const u16* Bsrc = netT + ((size_t)b * 4096 + s * 1024) * 256;
  const int srow = tid >> 5;       // 0..15 (+ i*16)
  const int sslot = tid & 31;      // 16B slot within row
  auto stage = [&](int c, int buf) {
    const u16* src = Bsrc + (size_t)c * 32 * 256;
#pragma unroll
    for (int i = 0; i < 2; ++i) {
      const int row = i * 16 + srow;
      const int scol = ((sslot ^ (row & 7)) * 8);
      async16(src + row * 256 + scol, &Bs[buf][i * 4096 + tid * 8]);
    }
  };

  f32x4 cacc[2] = {};          // ctx accum: d-group wq x e (wn*32 + ei*16)
  f32x4 sacc = {};             // rowsums (wn==0 waves only)
  bf16x8 ones8;
#pragma unroll
  for (int j = 0; j < 8; ++j) ((u16*)&ones8)[j] = 0x3F80;  // bf16 1.0

  // ctx accumulate from ekv buffer q (K = one 32-n chunk)
  auto ctx_acc = [&](int q) {
    const int d = wq * 16 + lr;
    bf16x8 ekf = *(const bf16x8*)&ekL[q][d * 32 + ((lg ^ (d & 3)) * 8)];
#pragma unroll
    for (int ei = 0; ei < 2; ++ei) {
      const int e = wn * 32 + ei * 16 + lr;
      bf16x8 vf = *(const bf16x8*)&vL[q][e * 32 + ((lg ^ (e & 3)) * 8)];
      cacc[ei] = __builtin_amdgcn_mfma_f32_16x16x32_bf16(ekf, vf, cacc[ei], 0, 0, 0);
    }
    if (wn == 0)
      sacc = __builtin_amdgcn_mfma_f32_16x16x32_bf16(ekf, ones8, sacc, 0, 0, 0);
  };

  stage(0, 0);
  const int nrow = wn * 16 + lr;

  for (int c = 0; c < 32; ++c) {
    const int p = c & 1;
    // single barrier: drains my stage(c) vmem (vmcnt 0) and all ds ops
    // (lgkmcnt 0) -> Bs[p] resident; ekv(c-1) visible; Bs[p^1]/ekv[p]
    // readers all completed block-wide.
    __syncthreads();
    if (c + 1 < 32) stage(c + 1, p ^ 1);   // safe: issued after the barrier

    // ---- merged MFMA region: ctx(c-1) + kv(c), 4 independent kv chains ----
    f32x4 kvA[2] = {}, kvB[2] = {};
    __builtin_amdgcn_s_setprio(1);
    if (c > 0) ctx_acc(p ^ 1);             // ekv written in iter c-1
#pragma unroll
    for (int kk = 0; kk < 4; ++kk) {
      bf16x8 bf0 = *(const bf16x8*)&Bs[p][nrow * 256 + ((((2 * kk) * 4 + lg) ^ (nrow & 7)) * 8)];
      bf16x8 bf1 = *(const bf16x8*)&Bs[p][nrow * 256 + ((((2 * kk + 1) * 4 + lg) ^ (nrow & 7)) * 8)];
      kvA[0] = __builtin_amdgcn_mfma_f32_16x16x32_bf16(af[0][2 * kk], bf0, kvA[0], 0, 0, 0);
      kvA[1] = __builtin_amdgcn_mfma_f32_16x16x32_bf16(af[1][2 * kk], bf0, kvA[1], 0, 0, 0);
      kvB[0] = __builtin_amdgcn_mfma_f32_16x16x32_bf16(af[0][2 * kk + 1], bf1, kvB[0], 0, 0, 0);
      kvB[1] = __builtin_amdgcn_mfma_f32_16x16x32_bf16(af[1][2 * kk + 1], bf1, kvB[1], 0, 0, 0);
    }
    __builtin_amdgcn_s_setprio(0);

    // ---- exp (k-half) + cheap-RNE bf16 + write to swizzled ekv[p] ----
    u16* dstL = isK ? ekL[p] : vL[p];
#pragma unroll
    for (int mi = 0; mi < 2; ++mi) {
      f32x4 kv4 = kvA[mi] + kvB[mi];
#pragma unroll
      for (int j = 0; j < 4; ++j) {
        float v = kv4[j];
        if (isK) v = __expf(v);
        const u32 u = __float_as_uint(v);
        const u16 bv = (u16)((u + 0x8000u) >> 16);       // cheap RNE
        const int dd = (wq & 1) * 32 + mi * 16 + lg * 4 + j;   // 0..63
        dstL[dd * 32 + (((nrow >> 3) ^ (dd & 3)) * 8) + (nrow & 7)] = bv;
      }
    }
  }
  __syncthreads();                 // ekv(31) visible
  ctx_acc(1);                      // ctx(31): buf 31&1 = 1

  // ---- store partials ----
  float* cp = ctxp + (((size_t)(b * 8 + h) * 4 + s) * 4096);
#pragma unroll
  for (int ei = 0; ei < 2; ++ei)
#pragma unroll
    for (int j = 0; j < 4; ++j) {
      const int d = wq * 16 + lg * 4 + j;
      const int e = wn * 32 + ei * 16 + lr;
      cp[d * 64 + e] = cacc[ei][j];
    }
  if (wn == 0 && lr == 0) {
#pragma unroll
    for (int j = 0; j < 4; ++j)
      sump[((size_t)(b * 8 + h) * 4 + s) * 64 + wq * 16 + lg * 4 + j] = sacc[j];
  }
}

// ---------------- fold_w2: reduce 4 partials, normalize, fold w_out ----------
__global__ __launch_bounds__(256) void fold_w2(const float* __restrict__ ctxp,
                                               const float* __restrict__ sump,
                                               const float* __restrict__ wout,
                                               u16* __restrict__ W2) {
  __shared__ float cl[16 * 64];
  __shared__ float sl[16];
  const int bh = blockIdx.x, dq = blockIdx.y;
  const int b = bh >> 3, h = bh & 7;
  const int tid = threadIdx.x;
  f32x4 v4 = {0.f, 0.f, 0.f, 0.f};
#pragma unroll
  for (int ch = 0; ch < 4; ++ch)
    v4 += *(const f32x4*)(ctxp + ((size_t)bh * 4 + ch) * 4096 + dq * 1024 + tid * 4);
  *(f32x4*)&cl[tid * 4] = v4;
  if (tid < 16) {
    float ss = 0.f;
#pragma unroll
    for (int ch = 0; ch < 4; ++ch)
      ss += sump[((size_t)bh * 4 + ch) * 64 + dq * 16 + tid];
    sl[tid] = ss;
  }
  __syncthreads();
  const int c = tid;
  f32x4 wv[16];
  const float* wrow = wout + (size_t)c * 512 + h * 64;
#pragma unroll
  for (int i = 0; i < 16; ++i) wv[i] = *(const f32x4*)(wrow + i * 4);
#pragma unroll
  for (int d = 0; d < 16; ++d) {
    f32x4 s4 = {0.f, 0.f, 0.f, 0.f};
#pragma unroll
    for (int e4 = 0; e4 < 16; ++e4) {
      f32x4 cv = *(const f32x4*)&cl[d * 64 + e4 * 4];
      s4 += wv[e4] * cv;
    }
    const float s = (s4[0] + s4[1] + s4[2] + s4[3]) / sl[d];
    W2[((size_t)b * 256 + c) * 512 + h * 64 + dq * 16 + d] = f2bf(s);
  }
}

// ---------------- gemm128: C[128x128] = A[128xK] * B[128xK]^T ----------------
// MODE 1: f32 out + bias; flat 1D grid with XCD-aware decode: both mt-blocks
//   of an (nt,b) land on one XCD 8-apart in dispatch order (netT L2-shared);
//   each XCD owns 2 batches (4MB netT = L2).
// MODE 2: bf16 plain (W3), standard 3D grid.
template <int LD, int NK, int MODE>
__global__ __launch_bounds__(256) void gemm128(const u16* __restrict__ A,
                                               const u16* __restrict__ B,
                                               size_t aStride, size_t bStride,
                                               void* __restrict__ O0,
                                               const float* __restrict__ bias) {
  __shared__ __align__(16) u16 SM[32768];
  int b, mt, nt;
  if constexpr (MODE == 1) {
    const int flat = blockIdx.x;
    const int xcd = flat & 7, r = flat >> 3;   // r 0..127
    b = 2 * xcd + (r >> 6);
    nt = (r & 63) >> 1;
    mt = r & 1;
  } else {
    b = blockIdx.z; mt = blockIdx.y; nt = blockIdx.x;
  }
  const int tid = threadIdx.x, lane = tid & 63, wid = tid >> 6;
  const int wr = wid >> 1, wc = wid & 1, lr = lane & 15, lg = lane >> 4;
  const u16* Ap = A + (size_t)b * aStride + (size_t)mt * 128 * LD;
  const u16* Bp = B + (size_t)b * bStride + (size_t)nt * 128 * LD;

  auto stage = [&](int buf, int ks) {
    const int k0 = ks * 64;
#pragma unroll
    for (int i = 0; i < 4; ++i) {
      const int idx = i * 2048 + tid * 8;
      const int r2 = idx >> 6, c2 = idx & 63;
      async16(Ap + (size_t)r2 * LD + k0 + c2, SM + buf * 8192 + i * 2048 + wid * 512);
      async16(Bp + (size_t)r2 * LD + k0 + c2, SM + 16384 + buf * 8192 + i * 2048 + wid * 512);
    }
  };

  f32x4 acc[4][4] = {};
  stage(0, 0);
  asm volatile("s_waitcnt vmcnt(0)" ::: "memory");
  __syncthreads();
  for (int ks = 0; ks < NK; ++ks) {
    const int buf = ks & 1;
    if (ks + 1 < NK) stage(buf ^ 1, ks + 1);
    const u16* Ab = SM + buf * 8192;
    const u16* Bb = SM + 16384 + buf * 8192;
#pragma unroll
    for (int kk = 0; kk < 2; ++kk) {
      bf16x8 afm[4], bfr[4];
#pragma unroll
      for (int mi = 0; mi < 4; ++mi)
        afm[mi] = *(const bf16x8*)(Ab + (wr * 64 + mi * 16 + lr) * 64 + kk * 32 + lg * 8);
#pragma unroll
      for (int ni = 0; ni < 4; ++ni)
        bfr[ni] = *(const bf16x8*)(Bb + (wc * 64 + ni * 16 + lr) * 64 + kk * 32 + lg * 8);
#pragma unroll
      for (int mi = 0; mi < 4; ++mi)
#pragma unroll
        for (int ni = 0; ni < 4; ++ni)
          acc[mi][ni] = __builtin_amdgcn_mfma_f32_16x16x32_bf16(afm[mi], bfr[ni], acc[mi][ni], 0, 0, 0);
    }
    asm volatile("s_waitcnt vmcnt(0)" ::: "memory");
    __syncthreads();
  }

  if constexpr (MODE == 2) {               // bf16 store (W3)
    u16* Cs = SM;
#pragma unroll
    for (int mi = 0; mi < 4; ++mi)
#pragma unroll
      for (int ni = 0; ni < 4; ++ni)
#pragma unroll
        for (int j = 0; j < 4; ++j)
          Cs[(wr * 64 + mi * 16 + lg * 4 + j) * 128 + wc * 64 + ni * 16 + lr] =
              f2bf(acc[mi][ni][j]);
    __syncthreads();
    u16* dst = (u16*)O0;
#pragma unroll
    for (int p = 0; p < 8; ++p) {
      const int idx = p * 2048 + tid * 8;
      const int r2 = idx >> 7, cc = idx & 127;
      *(u32x4*)(dst + ((size_t)b * 256 + mt * 128 + r2) * 256 + nt * 128 + cc) =
          *(const u32x4*)(Cs + idx);
    }
  } else {                                  // MODE 1: f32 + bias
    float* Cf = (float*)SM;                 // 64KB: 128x128 f32
#pragma unroll
    for (int mi = 0; mi < 4; ++mi)
#pragma unroll
      for (int ni = 0; ni < 4; ++ni)
#pragma unroll
        for (int j = 0; j < 4; ++j) {
          const int row = wr * 64 + mi * 16 + lg * 4 + j;
          Cf[row * 128 + wc * 64 + ni * 16 + lr] = acc[mi][ni][j] + bias[mt * 128 + row];
        }
    __syncthreads();
    float* op = (float*)O0;
#pragma unroll
    for (int p = 0; p < 16; ++p) {
      const int idx = p * 1024 + tid * 4;
      const int r2 = idx >> 7, cc = idx & 127;
      *(f32x4*)(op + ((size_t)b * 256 + mt * 128 + r2) * 4096 + nt * 128 + cc) =
          *(const f32x4*)(Cf + idx);
    }
  }
}

// ---------------------------------------------------------------------------
extern "C" void kernel_launch(void* const* d_in, const int* in_sizes, int n_in,
                              void* d_out, int out_size, void* d_ws, size_t ws_size,
                              hipStream_t stream) {
  const float* net  = (const float*)d_in[0];   // [16][256][4096]
  const float* wqkv = (const float*)d_in[1];   // [1536][256]
  const float* wout = (const float*)d_in[2];   // [256][512]
  const float* bout = (const float*)d_in[3];   // [256]
  float* out = (float*)d_out;

  char* ws = (char*)d_ws;
  u16*   netT = (u16*)(ws + 0);
  float* ctxp = (float*)(ws + 33554432);
  float* sump = (float*)(ws + 41943040);
  u16*   W2   = (u16*)(ws + 42074112);
  u16*   W3   = (u16*)(ws + 46268416);
  u16*   wqTb = (u16*)(ws + 48365568);

  // net (b,c,n) -> netT (b,n,c) bf16
  transpose_cast_g<<<dim3(64, 4, 16), 256, 0, stream>>>(net, netT, 256, 4096);
  // w_q (rows 0..511) [512][256] -> wqTb [256][512] bf16
  transpose_cast_g<<<dim3(4, 8, 1), 256, 0, stream>>>(wqkv, wqTb, 512, 256);
  // fused kv + ctx (wkv cast in-reg; ek/vv never hit HBM)
  kv_ctx_fused<<<512, 512, 0, stream>>>(wqkv, netT, ctxp, sump);
  // reduce partials + normalize + fold with w_out
  fold_w2<<<dim3(128, 4), 256, 0, stream>>>(ctxp, sump, wout, W2);
  // W3[b] = W2[b] @ wqT : M=256 K=512 N=256
  gemm128<512, 8, 2><<<dim3(2, 2, 16), 256, 0, stream>>>(
      W2, wqTb, (size_t)256 * 512, 0, W3, nullptr);
  // out = W3 @ netT^T + b_out : M=256 K=256 N=4096 (flat XCD-aware grid)
  gemm128<256, 4, 1><<<dim3(1024, 1, 1), 256, 0, stream>>>(
      W3, netT, (size_t)256 * 256, (size_t)4096 * 256, out, bout);
}

// Round 15
// 113.862 us; speedup vs baseline: 1.1116x; 1.1116x over previous
//
#include <hip/hip_runtime.h>

// ---------------------------------------------------------------------------
// LinearDepthWiseAttention, round 15: REVERT to round-13 (= round-10 best,
// 114.0us, twice-verified). r14's in-reg weight cast doubled FETCH (18.5->
// 40.3MB: 512 blocks x 128KB redundant f32 weight reads) -> fused 53.5->71.4.
//   kv   = w_qkv[512:1536] @ net ; ek = exp(k)      (never hits HBM)
//   ctx[b,h] += ek_h @ v_h^T ; rowsums via all-ones B-frag MFMA
//   W2 = fold(w_out, ctx/sum) ; W3[b] = W2[b] @ w_q^T ; out = W3 @ net + b_out
// kv_ctx_fused: 32-n chunks, Bs dbuf via global_load_lds (pre-swizzled src),
//   ekv dbuf, ONE __syncthreads/chunk, merged ctx(c-1)+kv(c) MFMA region
//   under setprio; scalar ekv stores (conflicts measured non-critical).
// gemm_out: flat XCD-aware decode (mt-pair co-located; 2 batches/XCD = L2).
// Workspace:
//   netT  [16][4096][256] bf16 @ 0          (33554432)
//   ctxp  [128][4][64][64] f32 @ 33554432   (8388608)
//   sump  [128][4][64]     f32 @ 41943040   (131072)
//   W2    [16][256][512]  bf16 @ 42074112   (4194304)
//   W3    [16][256][256]  bf16 @ 46268416   (2097152)
//   wkv   [1024][256]     bf16 @ 48365568   (524288)
//   wqTb  [256][512]      bf16 @ 48889856   (262144)
// ---------------------------------------------------------------------------

typedef unsigned short u16;
typedef unsigned int u32;
typedef __attribute__((ext_vector_type(4))) u16 u16x4;
typedef __attribute__((ext_vector_type(4))) u32 u32x4;
typedef __attribute__((ext_vector_type(4))) float f32x4;
typedef __attribute__((ext_vector_type(8))) short bf16x8;

__device__ __forceinline__ u16 f2bf(float f) {
  union { float f; u32 u; } x; x.f = f;
  u32 r = x.u + 0x7fffu + ((x.u >> 16) & 1u);   // round-to-nearest-even
  return (u16)(r >> 16);
}

// async global->LDS, 16B per lane; LDS dest must be wave-uniform base + lane*16.
__device__ __forceinline__ void async16(const u16* g, u16* l) {
  __builtin_amdgcn_global_load_lds(
      (const __attribute__((address_space(1))) void*)g,
      (__attribute__((address_space(3))) void*)l, 16, 0, 0);
}

// ---------------- cast w_qkv[512:1536] to bf16 ----------------
__global__ __launch_bounds__(256) void cast_w(const float* __restrict__ w,
                                              u16* __restrict__ o) {
  int i = (blockIdx.x * 256 + threadIdx.x) * 4;
  f32x4 v = *(const f32x4*)(w + i);
  u16x4 u;
  u[0] = f2bf(v[0]); u[1] = f2bf(v[1]); u[2] = f2bf(v[2]); u[3] = f2bf(v[3]);
  *(u16x4*)(o + i) = u;
}

// ---------------- generic transpose+cast: in[b][R][C] f32 -> out[b][C][R] bf16 ----
__global__ __launch_bounds__(256) void transpose_cast_g(const float* __restrict__ in,
                                                        u16* __restrict__ out,
                                                        int R, int C) {
  __shared__ float t[64][65];
  const int b = blockIdx.z, r0 = blockIdx.y * 64, c0 = blockIdx.x * 64;
  const float* ip = in + (size_t)b * R * C;
  u16* op = out + (size_t)b * R * C;
  const int tid = threadIdx.x;
  const int col4 = (tid & 15) * 4, rr0 = tid >> 4;
#pragma unroll
  for (int i = 0; i < 4; ++i) {
    int r = rr0 + i * 16;
    f32x4 v = *(const f32x4*)(ip + (size_t)(r0 + r) * C + c0 + col4);
    t[r][col4 + 0] = v[0]; t[r][col4 + 1] = v[1];
    t[r][col4 + 2] = v[2]; t[r][col4 + 3] = v[3];
  }
  __syncthreads();
  const int cc4 = (tid & 15) * 4, nr0 = tid >> 4;
#pragma unroll
  for (int i = 0; i < 4; ++i) {
    int nr = nr0 + i * 16;
    u16x4 u;
    u[0] = f2bf(t[cc4 + 0][nr]); u[1] = f2bf(t[cc4 + 1][nr]);
    u[2] = f2bf(t[cc4 + 2][nr]); u[3] = f2bf(t[cc4 + 3][nr]);
    *(u16x4*)(op + (size_t)(c0 + nr) * R + r0 + cc4) = u;
  }
}

// ---------------- fused kv + ctx (32-n chunks, 48KB LDS, 1 barrier/chunk) ----
// 512 threads = 8 waves: wq = wid&3 (32-row quarter of 128 kv rows),
// wn = wid>>2 (16-n half of the 32-n chunk). Per chunk c (32 chunks):
//   [__syncthreads]  (drains stage(c) vmem + ekv(c-1)/ctx(c-2) ds ops)
//   [stage(c+1) -> Bs[p^1]]          (Bs[p^1] readers kv(c-1) drained at bar)
//   [setprio; ctx(c-1) from ekv[p^1]; kv(c) from Bs[p]; setprio0]
//   [exp + cheap-RNE + write ekv[p]] (ekv[p] readers ctx(c-2) drained at bar)
__global__ __launch_bounds__(512, 4) void kv_ctx_fused(
    const u16* __restrict__ wkv,   // [1024][256] bf16 (k rows 0..511, v 512..1023)
    const u16* __restrict__ netT,  // [16][4096][256] bf16
    float* __restrict__ ctxp,      // [128][4][64][64]
    float* __restrict__ sump) {    // [128][4][64]
  __shared__ __align__(16) u16 Bs[2][8192];    // 32KB: [buf][32 n][256 c] swizzled
  __shared__ __align__(16) u16 ekL[2][2048];   // 8KB [buf][64 d][32 n] swizzled
  __shared__ __align__(16) u16 vL[2][2048];    // 8KB [buf][64 e][32 n] swizzled

  // XCD-aware decode: xcd = flat&7 hosts batches {2*xcd, 2*xcd+1} only.
  const int flat = blockIdx.x;
  const int xcd = flat & 7, inner = flat >> 3;
  const int b = 2 * xcd + (inner >> 5);
  const int h = (inner >> 2) & 7;
  const int s = inner & 3;

  const int tid = threadIdx.x, lane = tid & 63, wid = tid >> 6;
  const int wq = wid & 3, wn = wid >> 2;
  const int lr = lane & 15, lg = lane >> 4;
  const bool isK = (wq < 2);

  // ---- A-frags in registers: 32 rows x 256 K per wave (64 VGPR) ----
  bf16x8 af[2][8];
#pragma unroll
  for (int mi = 0; mi < 2; ++mi) {
    const int r = wq * 32 + mi * 16 + lr;                  // 0..127
    const int grow = (r < 64) ? h * 64 + r : 512 + h * 64 + (r - 64);
#pragma unroll
    for (int kk = 0; kk < 8; ++kk)
      af[mi][kk] = *(const bf16x8*)(wkv + (size_t)grow * 256 + kk * 32 + lg * 8);
  }

  const u16* Bsrc = netT + ((size_t)b * 4096 + s * 1024) * 256;
  const int srow = tid >> 5;       // 0..15 (+ i*16)
  const int sslot = tid & 31;      // 16B slot within row
  auto stage = [&](int c, int buf) {
    const u16* src = Bsrc + (size_t)c * 32 * 256;
#pragma unroll
    for (int i = 0; i < 2; ++i) {
      const int row = i * 16 + srow;
      const int scol = ((sslot ^ (row & 7)) * 8);
      async16(src + row * 256 + scol, &Bs[buf][i * 4096 + tid * 8]);
    }
  };

  f32x4 cacc[2] = {};          // ctx accum: d-group wq x e (wn*32 + ei*16)
  f32x4 sacc = {};             // rowsums (wn==0 waves only)
  bf16x8 ones8;
#pragma unroll
  for (int j = 0; j < 8; ++j) ((u16*)&ones8)[j] = 0x3F80;  // bf16 1.0

  // ctx accumulate from ekv buffer q (K = one 32-n chunk)
  auto ctx_acc = [&](int q) {
    const int d = wq * 16 + lr;
    bf16x8 ekf = *(const bf16x8*)&ekL[q][d * 32 + ((lg ^ (d & 3)) * 8)];
#pragma unroll
    for (int ei = 0; ei < 2; ++ei) {
      const int e = wn * 32 + ei * 16 + lr;
      bf16x8 vf = *(const bf16x8*)&vL[q][e * 32 + ((lg ^ (e & 3)) * 8)];
      cacc[ei] = __builtin_amdgcn_mfma_f32_16x16x32_bf16(ekf, vf, cacc[ei], 0, 0, 0);
    }
    if (wn == 0)
      sacc = __builtin_amdgcn_mfma_f32_16x16x32_bf16(ekf, ones8, sacc, 0, 0, 0);
  };

  stage(0, 0);
  const int nrow = wn * 16 + lr;

  for (int c = 0; c < 32; ++c) {
    const int p = c & 1;
    // single barrier: drains my stage(c) vmem (vmcnt 0) and all ds ops
    // (lgkmcnt 0) -> Bs[p] resident for all; ekv(c-1) visible; all reads of
    // Bs[p^1] (kv(c-1)) and ekv[p] (ctx(c-2)) completed block-wide.
    __syncthreads();
    if (c + 1 < 32) stage(c + 1, p ^ 1);   // safe: issued after the barrier

    // ---- merged MFMA region: ctx(c-1) + kv(c) ----
    f32x4 kvacc[2] = {};
    __builtin_amdgcn_s_setprio(1);
    if (c > 0) ctx_acc(p ^ 1);             // ekv written in iter c-1
#pragma unroll
    for (int kk = 0; kk < 8; ++kk) {
      bf16x8 bfr = *(const bf16x8*)&Bs[p][nrow * 256 + (((kk * 4 + lg) ^ (nrow & 7)) * 8)];
      kvacc[0] = __builtin_amdgcn_mfma_f32_16x16x32_bf16(af[0][kk], bfr, kvacc[0], 0, 0, 0);
      kvacc[1] = __builtin_amdgcn_mfma_f32_16x16x32_bf16(af[1][kk], bfr, kvacc[1], 0, 0, 0);
    }
    __builtin_amdgcn_s_setprio(0);

    // ---- exp (k-half) + cheap-RNE bf16 + write to swizzled ekv[p] ----
    u16* dstL = isK ? ekL[p] : vL[p];
#pragma unroll
    for (int mi = 0; mi < 2; ++mi)
#pragma unroll
      for (int j = 0; j < 4; ++j) {
        float v = kvacc[mi][j];
        if (isK) v = __expf(v);
        const u32 u = __float_as_uint(v);
        const u16 bv = (u16)((u + 0x8000u) >> 16);       // cheap RNE
        const int dd = (wq & 1) * 32 + mi * 16 + lg * 4 + j;   // 0..63
        dstL[dd * 32 + (((nrow >> 3) ^ (dd & 3)) * 8) + (nrow & 7)] = bv;
      }
  }
  __syncthreads();                 // ekv(31) visible
  ctx_acc(1);                      // ctx(31): buf 31&1 = 1

  // ---- store partials ----
  float* cp = ctxp + (((size_t)(b * 8 + h) * 4 + s) * 4096);
#pragma unroll
  for (int ei = 0; ei < 2; ++ei)
#pragma unroll
    for (int j = 0; j < 4; ++j) {
      const int d = wq * 16 + lg * 4 + j;
      const int e = wn * 32 + ei * 16 + lr;
      cp[d * 64 + e] = cacc[ei][j];
    }
  if (wn == 0 && lr == 0) {
#pragma unroll
    for (int j = 0; j < 4; ++j)
      sump[((size_t)(b * 8 + h) * 4 + s) * 64 + wq * 16 + lg * 4 + j] = sacc[j];
  }
}

// ---------------- fold_w2: reduce 4 partials, normalize, fold w_out ----------
__global__ __launch_bounds__(256) void fold_w2(const float* __restrict__ ctxp,
                                               const float* __restrict__ sump,
                                               const float* __restrict__ wout,
                                               u16* __restrict__ W2) {
  __shared__ float cl[16 * 64];
  __shared__ float sl[16];
  const int bh = blockIdx.x, dq = blockIdx.y;
  const int b = bh >> 3, h = bh & 7;
  const int tid = threadIdx.x;
  f32x4 v4 = {0.f, 0.f, 0.f, 0.f};
#pragma unroll
  for (int ch = 0; ch < 4; ++ch)
    v4 += *(const f32x4*)(ctxp + ((size_t)bh * 4 + ch) * 4096 + dq * 1024 + tid * 4);
  *(f32x4*)&cl[tid * 4] = v4;
  if (tid < 16) {
    float ss = 0.f;
#pragma unroll
    for (int ch = 0; ch < 4; ++ch)
      ss += sump[((size_t)bh * 4 + ch) * 64 + dq * 16 + tid];
    sl[tid] = ss;
  }
  __syncthreads();
  const int c = tid;
  f32x4 wv[16];
  const float* wrow = wout + (size_t)c * 512 + h * 64;
#pragma unroll
  for (int i = 0; i < 16; ++i) wv[i] = *(const f32x4*)(wrow + i * 4);
#pragma unroll
  for (int d = 0; d < 16; ++d) {
    f32x4 s4 = {0.f, 0.f, 0.f, 0.f};
#pragma unroll
    for (int e4 = 0; e4 < 16; ++e4) {
      f32x4 cv = *(const f32x4*)&cl[d * 64 + e4 * 4];
      s4 += wv[e4] * cv;
    }
    const float s = (s4[0] + s4[1] + s4[2] + s4[3]) / sl[d];
    W2[((size_t)b * 256 + c) * 512 + h * 64 + dq * 16 + d] = f2bf(s);
  }
}

// ---------------- gemm128: C[128x128] = A[128xK] * B[128xK]^T ----------------
// MODE 1: f32 out + bias; flat 1D grid with XCD-aware decode: both mt-blocks
//   of an (nt,b) land on one XCD 8-apart in dispatch order (netT L2-shared);
//   each XCD owns 2 batches (4MB netT = L2).
// MODE 2: bf16 plain (W3), standard 3D grid.
template <int LD, int NK, int MODE>
__global__ __launch_bounds__(256) void gemm128(const u16* __restrict__ A,
                                               const u16* __restrict__ B,
                                               size_t aStride, size_t bStride,
                                               void* __restrict__ O0,
                                               const float* __restrict__ bias) {
  __shared__ __align__(16) u16 SM[32768];
  int b, mt, nt;
  if constexpr (MODE == 1) {
    const int flat = blockIdx.x;
    const int xcd = flat & 7, r = flat >> 3;   // r 0..127
    b = 2 * xcd + (r >> 6);
    nt = (r & 63) >> 1;
    mt = r & 1;
  } else {
    b = blockIdx.z; mt = blockIdx.y; nt = blockIdx.x;
  }
  const int tid = threadIdx.x, lane = tid & 63, wid = tid >> 6;
  const int wr = wid >> 1, wc = wid & 1, lr = lane & 15, lg = lane >> 4;
  const u16* Ap = A + (size_t)b * aStride + (size_t)mt * 128 * LD;
  const u16* Bp = B + (size_t)b * bStride + (size_t)nt * 128 * LD;

  auto stage = [&](int buf, int ks) {
    const int k0 = ks * 64;
#pragma unroll
    for (int i = 0; i < 4; ++i) {
      const int idx = i * 2048 + tid * 8;
      const int r2 = idx >> 6, c2 = idx & 63;
      async16(Ap + (size_t)r2 * LD + k0 + c2, SM + buf * 8192 + i * 2048 + wid * 512);
      async16(Bp + (size_t)r2 * LD + k0 + c2, SM + 16384 + buf * 8192 + i * 2048 + wid * 512);
    }
  };

  f32x4 acc[4][4] = {};
  stage(0, 0);
  asm volatile("s_waitcnt vmcnt(0)" ::: "memory");
  __syncthreads();
  for (int ks = 0; ks < NK; ++ks) {
    const int buf = ks & 1;
    if (ks + 1 < NK) stage(buf ^ 1, ks + 1);
    const u16* Ab = SM + buf * 8192;
    const u16* Bb = SM + 16384 + buf * 8192;
#pragma unroll
    for (int kk = 0; kk < 2; ++kk) {
      bf16x8 afm[4], bfr[4];
#pragma unroll
      for (int mi = 0; mi < 4; ++mi)
        afm[mi] = *(const bf16x8*)(Ab + (wr * 64 + mi * 16 + lr) * 64 + kk * 32 + lg * 8);
#pragma unroll
      for (int ni = 0; ni < 4; ++ni)
        bfr[ni] = *(const bf16x8*)(Bb + (wc * 64 + ni * 16 + lr) * 64 + kk * 32 + lg * 8);
#pragma unroll
      for (int mi = 0; mi < 4; ++mi)
#pragma unroll
        for (int ni = 0; ni < 4; ++ni)
          acc[mi][ni] = __builtin_amdgcn_mfma_f32_16x16x32_bf16(afm[mi], bfr[ni], acc[mi][ni], 0, 0, 0);
    }
    asm volatile("s_waitcnt vmcnt(0)" ::: "memory");
    __syncthreads();
  }

  if constexpr (MODE == 2) {               // bf16 store (W3)
    u16* Cs = SM;
#pragma unroll
    for (int mi = 0; mi < 4; ++mi)
#pragma unroll
      for (int ni = 0; ni < 4; ++ni)
#pragma unroll
        for (int j = 0; j < 4; ++j)
          Cs[(wr * 64 + mi * 16 + lg * 4 + j) * 128 + wc * 64 + ni * 16 + lr] =
              f2bf(acc[mi][ni][j]);
    __syncthreads();
    u16* dst = (u16*)O0;
#pragma unroll
    for (int p = 0; p < 8; ++p) {
      const int idx = p * 2048 + tid * 8;
      const int r2 = idx >> 7, cc = idx & 127;
      *(u32x4*)(dst + ((size_t)b * 256 + mt * 128 + r2) * 256 + nt * 128 + cc) =
          *(const u32x4*)(Cs + idx);
    }
  } else {                                  // MODE 1: f32 + bias
    float* Cf = (float*)SM;                 // 64KB: 128x128 f32
#pragma unroll
    for (int mi = 0; mi < 4; ++mi)
#pragma unroll
      for (int ni = 0; ni < 4; ++ni)
#pragma unroll
        for (int j = 0; j < 4; ++j) {
          const int row = wr * 64 + mi * 16 + lg * 4 + j;
          Cf[row * 128 + wc * 64 + ni * 16 + lr] = acc[mi][ni][j] + bias[mt * 128 + row];
        }
    __syncthreads();
    float* op = (float*)O0;
#pragma unroll
    for (int p = 0; p < 16; ++p) {
      const int idx = p * 1024 + tid * 4;
      const int r2 = idx >> 7, cc = idx & 127;
      *(f32x4*)(op + ((size_t)b * 256 + mt * 128 + r2) * 4096 + nt * 128 + cc) =
          *(const f32x4*)(Cf + idx);
    }
  }
}

// ---------------------------------------------------------------------------
extern "C" void kernel_launch(void* const* d_in, const int* in_sizes, int n_in,
                              void* d_out, int out_size, void* d_ws, size_t ws_size,
                              hipStream_t stream) {
  const float* net  = (const float*)d_in[0];   // [16][256][4096]
  const float* wqkv = (const float*)d_in[1];   // [1536][256]
  const float* wout = (const float*)d_in[2];   // [256][512]
  const float* bout = (const float*)d_in[3];   // [256]
  float* out = (float*)d_out;

  char* ws = (char*)d_ws;
  u16*   netT = (u16*)(ws + 0);
  float* ctxp = (float*)(ws + 33554432);
  float* sump = (float*)(ws + 41943040);
  u16*   W2   = (u16*)(ws + 42074112);
  u16*   W3   = (u16*)(ws + 46268416);
  u16*   wkv  = (u16*)(ws + 48365568);
  u16*   wqTb = (u16*)(ws + 48889856);

  // w_kv (rows 512..1535) -> bf16
  cast_w<<<256, 256, 0, stream>>>(wqkv + 512 * 256, wkv);
  // net (b,c,n) -> netT (b,n,c) bf16
  transpose_cast_g<<<dim3(64, 4, 16), 256, 0, stream>>>(net, netT, 256, 4096);
  // w_q (rows 0..511) [512][256] -> wqTb [256][512] bf16
  transpose_cast_g<<<dim3(4, 8, 1), 256, 0, stream>>>(wqkv, wqTb, 512, 256);
  // fused kv + ctx (ek/vv never hit HBM); 512 blocks, 32 chunks, 1 bar/chunk
  kv_ctx_fused<<<512, 512, 0, stream>>>(wkv, netT, ctxp, sump);
  // reduce partials + normalize + fold with w_out
  fold_w2<<<dim3(128, 4), 256, 0, stream>>>(ctxp, sump, wout, W2);
  // W3[b] = W2[b] @ wqT : M=256 K=512 N=256
  gemm128<512, 8, 2><<<dim3(2, 2, 16), 256, 0, stream>>>(
      W2, wqTb, (size_t)256 * 512, 0, W3, nullptr);
  // out = W3 @ netT^T + b_out : M=256 K=256 N=4096 (flat XCD-aware grid)
  gemm128<256, 4, 1><<<dim3(1024, 1, 1), 256, 0, stream>>>(
      W3, netT, (size_t)256 * 256, (size_t)4096 * 256, out, bout);
}

// Round 16
// 111.744 us; speedup vs baseline: 1.1327x; 1.0189x over previous
//
#include <hip/hip_runtime.h>

// ---------------------------------------------------------------------------
// LinearDepthWiseAttention, round 16: r15 (thrice-verified 113.9us) with the
// two tiny weight-prep kernels MERGED into one launch (prep_w: blocks 0..255
// = w_kv cast, 256..287 = w_q transpose). Bodies verbatim -> bit-identical.
//   kv   = w_qkv[512:1536] @ net ; ek = exp(k)      (never hits HBM)
//   ctx[b,h] += ek_h @ v_h^T ; rowsums via all-ones B-frag MFMA
//   W2 = fold(w_out, ctx/sum) ; W3[b] = W2[b] @ w_q^T ; out = W3 @ net + b_out
// kv_ctx_fused: 32-n chunks, Bs dbuf via global_load_lds (pre-swizzled src),
//   ekv dbuf, ONE __syncthreads/chunk, merged ctx(c-1)+kv(c) MFMA region
//   under setprio; scalar ekv stores (conflicts measured non-critical).
// gemm_out: flat XCD-aware decode (mt-pair co-located; 2 batches/XCD = L2).
// Workspace:
//   netT  [16][4096][256] bf16 @ 0          (33554432)
//   ctxp  [128][4][64][64] f32 @ 33554432   (8388608)
//   sump  [128][4][64]     f32 @ 41943040   (131072)
//   W2    [16][256][512]  bf16 @ 42074112   (4194304)
//   W3    [16][256][256]  bf16 @ 46268416   (2097152)
//   wkv   [1024][256]     bf16 @ 48365568   (524288)
//   wqTb  [256][512]      bf16 @ 48889856   (262144)
// ---------------------------------------------------------------------------

typedef unsigned short u16;
typedef unsigned int u32;
typedef __attribute__((ext_vector_type(4))) u16 u16x4;
typedef __attribute__((ext_vector_type(4))) u32 u32x4;
typedef __attribute__((ext_vector_type(4))) float f32x4;
typedef __attribute__((ext_vector_type(8))) short bf16x8;

__device__ __forceinline__ u16 f2bf(float f) {
  union { float f; u32 u; } x; x.f = f;
  u32 r = x.u + 0x7fffu + ((x.u >> 16) & 1u);   // round-to-nearest-even
  return (u16)(r >> 16);
}

// async global->LDS, 16B per lane; LDS dest must be wave-uniform base + lane*16.
__device__ __forceinline__ void async16(const u16* g, u16* l) {
  __builtin_amdgcn_global_load_lds(
      (const __attribute__((address_space(1))) void*)g,
      (__attribute__((address_space(3))) void*)l, 16, 0, 0);
}

// ---------------- prep_w: merged weight prep (1 launch instead of 2) --------
// blocks 0..255  : w_kv (rows 512..1535 of wqkv) f32 -> bf16 into wkv
// blocks 256..287: w_q (rows 0..511) [512][256] -> wqTb [256][512] bf16
__global__ __launch_bounds__(256) void prep_w(const float* __restrict__ wqkv,
                                              u16* __restrict__ wkv,
                                              u16* __restrict__ wqTb) {
  __shared__ float t[64][65];
  const int blk = blockIdx.x;
  const int tid = threadIdx.x;
  if (blk < 256) {                       // ---- cast_w body (verbatim) ----
    const float* w = wqkv + 512 * 256;
    int i = (blk * 256 + tid) * 4;
    f32x4 v = *(const f32x4*)(w + i);
    u16x4 u;
    u[0] = f2bf(v[0]); u[1] = f2bf(v[1]); u[2] = f2bf(v[2]); u[3] = f2bf(v[3]);
    *(u16x4*)(wkv + i) = u;
  } else {                               // ---- wq transpose body (verbatim) ----
    const int idx = blk - 256;           // 0..31
    const int c0 = (idx & 3) * 64, r0 = (idx >> 2) * 64;   // C=256, R=512
    const int col4 = (tid & 15) * 4, rr0 = tid >> 4;
#pragma unroll
    for (int i = 0; i < 4; ++i) {
      int r = rr0 + i * 16;
      f32x4 v = *(const f32x4*)(wqkv + (size_t)(r0 + r) * 256 + c0 + col4);
      t[r][col4 + 0] = v[0]; t[r][col4 + 1] = v[1];
      t[r][col4 + 2] = v[2]; t[r][col4 + 3] = v[3];
    }
    __syncthreads();
    const int cc4 = (tid & 15) * 4, nr0 = tid >> 4;
#pragma unroll
    for (int i = 0; i < 4; ++i) {
      int nr = nr0 + i * 16;
      u16x4 u;
      u[0] = f2bf(t[cc4 + 0][nr]); u[1] = f2bf(t[cc4 + 1][nr]);
      u[2] = f2bf(t[cc4 + 2][nr]); u[3] = f2bf(t[cc4 + 3][nr]);
      *(u16x4*)(wqTb + (size_t)(c0 + nr) * 512 + r0 + cc4) = u;
    }
  }
}

// ---------------- generic transpose+cast: in[b][R][C] f32 -> out[b][C][R] bf16 ----
__global__ __launch_bounds__(256) void transpose_cast_g(const float* __restrict__ in,
                                                        u16* __restrict__ out,
                                                        int R, int C) {
  __shared__ float t[64][65];
  const int b = blockIdx.z, r0 = blockIdx.y * 64, c0 = blockIdx.x * 64;
  const float* ip = in + (size_t)b * R * C;
  u16* op = out + (size_t)b * R * C;
  const int tid = threadIdx.x;
  const int col4 = (tid & 15) * 4, rr0 = tid >> 4;
#pragma unroll
  for (int i = 0; i < 4; ++i) {
    int r = rr0 + i * 16;
    f32x4 v = *(const f32x4*)(ip + (size_t)(r0 + r) * C + c0 + col4);
    t[r][col4 + 0] = v[0]; t[r][col4 + 1] = v[1];
    t[r][col4 + 2] = v[2]; t[r][col4 + 3] = v[3];
  }
  __syncthreads();
  const int cc4 = (tid & 15) * 4, nr0 = tid >> 4;
#pragma unroll
  for (int i = 0; i < 4; ++i) {
    int nr = nr0 + i * 16;
    u16x4 u;
    u[0] = f2bf(t[cc4 + 0][nr]); u[1] = f2bf(t[cc4 + 1][nr]);
    u[2] = f2bf(t[cc4 + 2][nr]); u[3] = f2bf(t[cc4 + 3][nr]);
    *(u16x4*)(op + (size_t)(c0 + nr) * R + r0 + cc4) = u;
  }
}

// ---------------- fused kv + ctx (32-n chunks, 48KB LDS, 1 barrier/chunk) ----
// 512 threads = 8 waves: wq = wid&3 (32-row quarter of 128 kv rows),
// wn = wid>>2 (16-n half of the 32-n chunk). Per chunk c (32 chunks):
//   [__syncthreads]  (drains stage(c) vmem + ekv(c-1)/ctx(c-2) ds ops)
//   [stage(c+1) -> Bs[p^1]]          (Bs[p^1] readers kv(c-1) drained at bar)
//   [setprio; ctx(c-1) from ekv[p^1]; kv(c) from Bs[p]; setprio0]
//   [exp + cheap-RNE + write ekv[p]] (ekv[p] readers ctx(c-2) drained at bar)
__global__ __launch_bounds__(512, 4) void kv_ctx_fused(
    const u16* __restrict__ wkv,   // [1024][256] bf16 (k rows 0..511, v 512..1023)
    const u16* __restrict__ netT,  // [16][4096][256] bf16
    float* __restrict__ ctxp,      // [128][4][64][64]
    float* __restrict__ sump) {    // [128][4][64]
  __shared__ __align__(16) u16 Bs[2][8192];    // 32KB: [buf][32 n][256 c] swizzled
  __shared__ __align__(16) u16 ekL[2][2048];   // 8KB [buf][64 d][32 n] swizzled
  __shared__ __align__(16) u16 vL[2][2048];    // 8KB [buf][64 e][32 n] swizzled

  // XCD-aware decode: xcd = flat&7 hosts batches {2*xcd, 2*xcd+1} only.
  const int flat = blockIdx.x;
  const int xcd = flat & 7, inner = flat >> 3;
  const int b = 2 * xcd + (inner >> 5);
  const int h = (inner >> 2) & 7;
  const int s = inner & 3;

  const int tid = threadIdx.x, lane = tid & 63, wid = tid >> 6;
  const int wq = wid & 3, wn = wid >> 2;
  const int lr = lane & 15, lg = lane >> 4;
  const bool isK = (wq < 2);

  // ---- A-frags in registers: 32 rows x 256 K per wave (64 VGPR) ----
  bf16x8 af[2][8];
#pragma unroll
  for (int mi = 0; mi < 2; ++mi) {
    const int r = wq * 32 + mi * 16 + lr;                  // 0..127
    const int grow = (r < 64) ? h * 64 + r : 512 + h * 64 + (r - 64);
#pragma unroll
    for (int kk = 0; kk < 8; ++kk)
      af[mi][kk] = *(const bf16x8*)(wkv + (size_t)grow * 256 + kk * 32 + lg * 8);
  }

  const u16* Bsrc = netT + ((size_t)b * 4096 + s * 1024) * 256;
  const int srow = tid >> 5;       // 0..15 (+ i*16)
  const int sslot = tid & 31;      // 16B slot within row
  auto stage = [&](int c, int buf) {
    const u16* src = Bsrc + (size_t)c * 32 * 256;
#pragma unroll
    for (int i = 0; i < 2; ++i) {
      const int row = i * 16 + srow;
      const int scol = ((sslot ^ (row & 7)) * 8);
      async16(src + row * 256 + scol, &Bs[buf][i * 4096 + tid * 8]);
    }
  };

  f32x4 cacc[2] = {};          // ctx accum: d-group wq x e (wn*32 + ei*16)
  f32x4 sacc = {};             // rowsums (wn==0 waves only)
  bf16x8 ones8;
#pragma unroll
  for (int j = 0; j < 8; ++j) ((u16*)&ones8)[j] = 0x3F80;  // bf16 1.0

  // ctx accumulate from ekv buffer q (K = one 32-n chunk)
  auto ctx_acc = [&](int q) {
    const int d = wq * 16 + lr;
    bf16x8 ekf = *(const bf16x8*)&ekL[q][d * 32 + ((lg ^ (d & 3)) * 8)];
#pragma unroll
    for (int ei = 0; ei < 2; ++ei) {
      const int e = wn * 32 + ei * 16 + lr;
      bf16x8 vf = *(const bf16x8*)&vL[q][e * 32 + ((lg ^ (e & 3)) * 8)];
      cacc[ei] = __builtin_amdgcn_mfma_f32_16x16x32_bf16(ekf, vf, cacc[ei], 0, 0, 0);
    }
    if (wn == 0)
      sacc = __builtin_amdgcn_mfma_f32_16x16x32_bf16(ekf, ones8, sacc, 0, 0, 0);
  };

  stage(0, 0);
  const int nrow = wn * 16 + lr;

  for (int c = 0; c < 32; ++c) {
    const int p = c & 1;
    // single barrier: drains my stage(c) vmem (vmcnt 0) and all ds ops
    // (lgkmcnt 0) -> Bs[p] resident for all; ekv(c-1) visible; all reads of
    // Bs[p^1] (kv(c-1)) and ekv[p] (ctx(c-2)) completed block-wide.
    __syncthreads();
    if (c + 1 < 32) stage(c + 1, p ^ 1);   // safe: issued after the barrier

    // ---- merged MFMA region: ctx(c-1) + kv(c) ----
    f32x4 kvacc[2] = {};
    __builtin_amdgcn_s_setprio(1);
    if (c > 0) ctx_acc(p ^ 1);             // ekv written in iter c-1
#pragma unroll
    for (int kk = 0; kk < 8; ++kk) {
      bf16x8 bfr = *(const bf16x8*)&Bs[p][nrow * 256 + (((kk * 4 + lg) ^ (nrow & 7)) * 8)];
      kvacc[0] = __builtin_amdgcn_mfma_f32_16x16x32_bf16(af[0][kk], bfr, kvacc[0], 0, 0, 0);
      kvacc[1] = __builtin_amdgcn_mfma_f32_16x16x32_bf16(af[1][kk], bfr, kvacc[1], 0, 0, 0);
    }
    __builtin_amdgcn_s_setprio(0);

    // ---- exp (k-half) + cheap-RNE bf16 + write to swizzled ekv[p] ----
    u16* dstL = isK ? ekL[p] : vL[p];
#pragma unroll
    for (int mi = 0; mi < 2; ++mi)
#pragma unroll
      for (int j = 0; j < 4; ++j) {
        float v = kvacc[mi][j];
        if (isK) v = __expf(v);
        const u32 u = __float_as_uint(v);
        const u16 bv = (u16)((u + 0x8000u) >> 16);       // cheap RNE
        const int dd = (wq & 1) * 32 + mi * 16 + lg * 4 + j;   // 0..63
        dstL[dd * 32 + (((nrow >> 3) ^ (dd & 3)) * 8) + (nrow & 7)] = bv;
      }
  }
  __syncthreads();                 // ekv(31) visible
  ctx_acc(1);                      // ctx(31): buf 31&1 = 1

  // ---- store partials ----
  float* cp = ctxp + (((size_t)(b * 8 + h) * 4 + s) * 4096);
#pragma unroll
  for (int ei = 0; ei < 2; ++ei)
#pragma unroll
    for (int j = 0; j < 4; ++j) {
      const int d = wq * 16 + lg * 4 + j;
      const int e = wn * 32 + ei * 16 + lr;
      cp[d * 64 + e] = cacc[ei][j];
    }
  if (wn == 0 && lr == 0) {
#pragma unroll
    for (int j = 0; j < 4; ++j)
      sump[((size_t)(b * 8 + h) * 4 + s) * 64 + wq * 16 + lg * 4 + j] = sacc[j];
  }
}

// ---------------- fold_w2: reduce 4 partials, normalize, fold w_out ----------
__global__ __launch_bounds__(256) void fold_w2(const float* __restrict__ ctxp,
                                               const float* __restrict__ sump,
                                               const float* __restrict__ wout,
                                               u16* __restrict__ W2) {
  __shared__ float cl[16 * 64];
  __shared__ float sl[16];
  const int bh = blockIdx.x, dq = blockIdx.y;
  const int b = bh >> 3, h = bh & 7;
  const int tid = threadIdx.x;
  f32x4 v4 = {0.f, 0.f, 0.f, 0.f};
#pragma unroll
  for (int ch = 0; ch < 4; ++ch)
    v4 += *(const f32x4*)(ctxp + ((size_t)bh * 4 + ch) * 4096 + dq * 1024 + tid * 4);
  *(f32x4*)&cl[tid * 4] = v4;
  if (tid < 16) {
    float ss = 0.f;
#pragma unroll
    for (int ch = 0; ch < 4; ++ch)
      ss += sump[((size_t)bh * 4 + ch) * 64 + dq * 16 + tid];
    sl[tid] = ss;
  }
  __syncthreads();
  const int c = tid;
  f32x4 wv[16];
  const float* wrow = wout + (size_t)c * 512 + h * 64;
#pragma unroll
  for (int i = 0; i < 16; ++i) wv[i] = *(const f32x4*)(wrow + i * 4);
#pragma unroll
  for (int d = 0; d < 16; ++d) {
    f32x4 s4 = {0.f, 0.f, 0.f, 0.f};
#pragma unroll
    for (int e4 = 0; e4 < 16; ++e4) {
      f32x4 cv = *(const f32x4*)&cl[d * 64 + e4 * 4];
      s4 += wv[e4] * cv;
    }
    const float s = (s4[0] + s4[1] + s4[2] + s4[3]) / sl[d];
    W2[((size_t)b * 256 + c) * 512 + h * 64 + dq * 16 + d] = f2bf(s);
  }
}

// ---------------- gemm128: C[128x128] = A[128xK] * B[128xK]^T ----------------
// MODE 1: f32 out + bias; flat 1D grid with XCD-aware decode: both mt-blocks
//   of an (nt,b) land on one XCD 8-apart in dispatch order (netT L2-shared);
//   each XCD owns 2 batches (4MB netT = L2).
// MODE 2: bf16 plain (W3), standard 3D grid.
template <int LD, int NK, int MODE>
__global__ __launch_bounds__(256) void gemm128(const u16* __restrict__ A,
                                               const u16* __restrict__ B,
                                               size_t aStride, size_t bStride,
                                               void* __restrict__ O0,
                                               const float* __restrict__ bias) {
  __shared__ __align__(16) u16 SM[32768];
  int b, mt, nt;
  if constexpr (MODE == 1) {
    const int flat = blockIdx.x;
    const int xcd = flat & 7, r = flat >> 3;   // r 0..127
    b = 2 * xcd + (r >> 6);
    nt = (r & 63) >> 1;
    mt = r & 1;
  } else {
    b = blockIdx.z; mt = blockIdx.y; nt = blockIdx.x;
  }
  const int tid = threadIdx.x, lane = tid & 63, wid = tid >> 6;
  const int wr = wid >> 1, wc = wid & 1, lr = lane & 15, lg = lane >> 4;
  const u16* Ap = A + (size_t)b * aStride + (size_t)mt * 128 * LD;
  const u16* Bp = B + (size_t)b * bStride + (size_t)nt * 128 * LD;

  auto stage = [&](int buf, int ks) {
    const int k0 = ks * 64;
#pragma unroll
    for (int i = 0; i < 4; ++i) {
      const int idx = i * 2048 + tid * 8;
      const int r2 = idx >> 6, c2 = idx & 63;
      async16(Ap + (size_t)r2 * LD + k0 + c2, SM + buf * 8192 + i * 2048 + wid * 512);
      async16(Bp + (size_t)r2 * LD + k0 + c2, SM + 16384 + buf * 8192 + i * 2048 + wid * 512);
    }
  };

  f32x4 acc[4][4] = {};
  stage(0, 0);
  asm volatile("s_waitcnt vmcnt(0)" ::: "memory");
  __syncthreads();
  for (int ks = 0; ks < NK; ++ks) {
    const int buf = ks & 1;
    if (ks + 1 < NK) stage(buf ^ 1, ks + 1);
    const u16* Ab = SM + buf * 8192;
    const u16* Bb = SM + 16384 + buf * 8192;
#pragma unroll
    for (int kk = 0; kk < 2; ++kk) {
      bf16x8 afm[4], bfr[4];
#pragma unroll
      for (int mi = 0; mi < 4; ++mi)
        afm[mi] = *(const bf16x8*)(Ab + (wr * 64 + mi * 16 + lr) * 64 + kk * 32 + lg * 8);
#pragma unroll
      for (int ni = 0; ni < 4; ++ni)
        bfr[ni] = *(const bf16x8*)(Bb + (wc * 64 + ni * 16 + lr) * 64 + kk * 32 + lg * 8);
#pragma unroll
      for (int mi = 0; mi < 4; ++mi)
#pragma unroll
        for (int ni = 0; ni < 4; ++ni)
          acc[mi][ni] = __builtin_amdgcn_mfma_f32_16x16x32_bf16(afm[mi], bfr[ni], acc[mi][ni], 0, 0, 0);
    }
    asm volatile("s_waitcnt vmcnt(0)" ::: "memory");
    __syncthreads();
  }

  if constexpr (MODE == 2) {               // bf16 store (W3)
    u16* Cs = SM;
#pragma unroll
    for (int mi = 0; mi < 4; ++mi)
#pragma unroll
      for (int ni = 0; ni < 4; ++ni)
#pragma unroll
        for (int j = 0; j < 4; ++j)
          Cs[(wr * 64 + mi * 16 + lg * 4 + j) * 128 + wc * 64 + ni * 16 + lr] =
              f2bf(acc[mi][ni][j]);
    __syncthreads();
    u16* dst = (u16*)O0;
#pragma unroll
    for (int p = 0; p < 8; ++p) {
      const int idx = p * 2048 + tid * 8;
      const int r2 = idx >> 7, cc = idx & 127;
      *(u32x4*)(dst + ((size_t)b * 256 + mt * 128 + r2) * 256 + nt * 128 + cc) =
          *(const u32x4*)(Cs + idx);
    }
  } else {                                  // MODE 1: f32 + bias
    float* Cf = (float*)SM;                 // 64KB: 128x128 f32
#pragma unroll
    for (int mi = 0; mi < 4; ++mi)
#pragma unroll
      for (int ni = 0; ni < 4; ++ni)
#pragma unroll
        for (int j = 0; j < 4; ++j) {
          const int row = wr * 64 + mi * 16 + lg * 4 + j;
          Cf[row * 128 + wc * 64 + ni * 16 + lr] = acc[mi][ni][j] + bias[mt * 128 + row];
        }
    __syncthreads();
    float* op = (float*)O0;
#pragma unroll
    for (int p = 0; p < 16; ++p) {
      const int idx = p * 1024 + tid * 4;
      const int r2 = idx >> 7, cc = idx & 127;
      *(f32x4*)(op + ((size_t)b * 256 + mt * 128 + r2) * 4096 + nt * 128 + cc) =
          *(const f32x4*)(Cf + idx);
    }
  }
}

// ---------------------------------------------------------------------------
extern "C" void kernel_launch(void* const* d_in, const int* in_sizes, int n_in,
                              void* d_out, int out_size, void* d_ws, size_t ws_size,
                              hipStream_t stream) {
  const float* net  = (const float*)d_in[0];   // [16][256][4096]
  const float* wqkv = (const float*)d_in[1];   // [1536][256]
  const float* wout = (const float*)d_in[2];   // [256][512]
  const float* bout = (const float*)d_in[3];   // [256]
  float* out = (float*)d_out;

  char* ws = (char*)d_ws;
  u16*   netT = (u16*)(ws + 0);
  float* ctxp = (float*)(ws + 33554432);
  float* sump = (float*)(ws + 41943040);
  u16*   W2   = (u16*)(ws + 42074112);
  u16*   W3   = (u16*)(ws + 46268416);
  u16*   wkv  = (u16*)(ws + 48365568);
  u16*   wqTb = (u16*)(ws + 48889856);

  // merged weight prep: w_kv cast (blocks 0..255) + w_q transpose (256..287)
  prep_w<<<288, 256, 0, stream>>>(wqkv, wkv, wqTb);
  // net (b,c,n) -> netT (b,n,c) bf16
  transpose_cast_g<<<dim3(64, 4, 16), 256, 0, stream>>>(net, netT, 256, 4096);
  // fused kv + ctx (ek/vv never hit HBM); 512 blocks, 32 chunks, 1 bar/chunk
  kv_ctx_fused<<<512, 512, 0, stream>>>(wkv, netT, ctxp, sump);
  // reduce partials + normalize + fold with w_out
  fold_w2<<<dim3(128, 4), 256, 0, stream>>>(ctxp, sump, wout, W2);
  // W3[b] = W2[b] @ wqT : M=256 K=512 N=256
  gemm128<512, 8, 2><<<dim3(2, 2, 16), 256, 0, stream>>>(
      W2, wqTb, (size_t)256 * 512, 0, W3, nullptr);
  // out = W3 @ netT^T + b_out : M=256 K=256 N=4096 (flat XCD-aware grid)
  gemm128<256, 4, 1><<<dim3(1024, 1, 1), 256, 0, stream>>>(
      W3, netT, (size_t)256 * 256, (size_t)4096 * 256, out, bout);
}

// Round 17
// 107.030 us; speedup vs baseline: 1.1825x; 1.0440x over previous
//
#include <hip/hip_runtime.h>

// ---------------------------------------------------------------------------
// LinearDepthWiseAttention, round 17: r16 (111.7us best) with prep_w merged
// into the net-transpose launch (prep_all): 6 -> 5 dispatches.
//   blocks 0..4095   : net (b,c,n) f32 -> netT (b,n,c) bf16   (verbatim)
//   blocks 4096..4351: w_kv (rows 512..1535) f32 -> bf16      (verbatim)
//   blocks 4352..4383: w_q (rows 0..511) -> wqTb [256][512]   (verbatim)
//   kv   = w_qkv[512:1536] @ net ; ek = exp(k)      (never hits HBM)
//   ctx[b,h] += ek_h @ v_h^T ; rowsums via all-ones B-frag MFMA
//   W2 = fold(w_out, ctx/sum) ; W3[b] = W2[b] @ w_q^T ; out = W3 @ net + b_out
// kv_ctx_fused: 32-n chunks, Bs dbuf via global_load_lds (pre-swizzled src),
//   ekv dbuf, ONE __syncthreads/chunk, merged ctx(c-1)+kv(c) MFMA region
//   under setprio; scalar ekv stores (conflicts measured non-critical).
// gemm_out: flat XCD-aware decode (mt-pair co-located; 2 batches/XCD = L2).
// Workspace:
//   netT  [16][4096][256] bf16 @ 0          (33554432)
//   ctxp  [128][4][64][64] f32 @ 33554432   (8388608)
//   sump  [128][4][64]     f32 @ 41943040   (131072)
//   W2    [16][256][512]  bf16 @ 42074112   (4194304)
//   W3    [16][256][256]  bf16 @ 46268416   (2097152)
//   wkv   [1024][256]     bf16 @ 48365568   (524288)
//   wqTb  [256][512]      bf16 @ 48889856   (262144)
// ---------------------------------------------------------------------------

typedef unsigned short u16;
typedef unsigned int u32;
typedef __attribute__((ext_vector_type(4))) u16 u16x4;
typedef __attribute__((ext_vector_type(4))) u32 u32x4;
typedef __attribute__((ext_vector_type(4))) float f32x4;
typedef __attribute__((ext_vector_type(8))) short bf16x8;

__device__ __forceinline__ u16 f2bf(float f) {
  union { float f; u32 u; } x; x.f = f;
  u32 r = x.u + 0x7fffu + ((x.u >> 16) & 1u);   // round-to-nearest-even
  return (u16)(r >> 16);
}

// async global->LDS, 16B per lane; LDS dest must be wave-uniform base + lane*16.
__device__ __forceinline__ void async16(const u16* g, u16* l) {
  __builtin_amdgcn_global_load_lds(
      (const __attribute__((address_space(1))) void*)g,
      (__attribute__((address_space(3))) void*)l, 16, 0, 0);
}

// ---------------- prep_all: net transpose + weight prep, ONE launch ---------
// blocks 0..4095   : net transpose (x = blk&63 n-tile, y = (blk>>6)&3 c-tile,
//                    z = blk>>8 batch) -- body verbatim from transpose_cast_g
// blocks 4096..4351: w_kv cast (verbatim cast_w body)
// blocks 4352..4383: w_q 64x64 transpose tile (verbatim)
__global__ __launch_bounds__(256) void prep_all(const float* __restrict__ net,
                                                u16* __restrict__ netT,
                                                const float* __restrict__ wqkv,
                                                u16* __restrict__ wkv,
                                                u16* __restrict__ wqTb) {
  __shared__ float t[64][65];
  const int blk = blockIdx.x;
  const int tid = threadIdx.x;
  if (blk < 4096) {                      // ---- net transpose (R=256,C=4096) ----
    const int b = blk >> 8, c0 = ((blk >> 6) & 3) * 64, n0 = (blk & 63) * 64;
    const float* ip = net + (size_t)b * 256 * 4096;
    u16* op = netT + (size_t)b * 256 * 4096;
    const int col4 = (tid & 15) * 4, rr0 = tid >> 4;
#pragma unroll
    for (int i = 0; i < 4; ++i) {
      int r = rr0 + i * 16;
      f32x4 v = *(const f32x4*)(ip + (size_t)(c0 + r) * 4096 + n0 + col4);
      t[r][col4 + 0] = v[0]; t[r][col4 + 1] = v[1];
      t[r][col4 + 2] = v[2]; t[r][col4 + 3] = v[3];
    }
    __syncthreads();
    const int cc4 = (tid & 15) * 4, nr0 = tid >> 4;
#pragma unroll
    for (int i = 0; i < 4; ++i) {
      int nr = nr0 + i * 16;
      u16x4 u;
      u[0] = f2bf(t[cc4 + 0][nr]); u[1] = f2bf(t[cc4 + 1][nr]);
      u[2] = f2bf(t[cc4 + 2][nr]); u[3] = f2bf(t[cc4 + 3][nr]);
      *(u16x4*)(op + (size_t)(n0 + nr) * 256 + c0 + cc4) = u;
    }
  } else if (blk < 4352) {               // ---- w_kv cast ----
    const float* w = wqkv + 512 * 256;
    int i = ((blk - 4096) * 256 + tid) * 4;
    f32x4 v = *(const f32x4*)(w + i);
    u16x4 u;
    u[0] = f2bf(v[0]); u[1] = f2bf(v[1]); u[2] = f2bf(v[2]); u[3] = f2bf(v[3]);
    *(u16x4*)(wkv + i) = u;
  } else {                               // ---- w_q transpose (R=512,C=256) ----
    const int idx = blk - 4352;          // 0..31
    const int c0 = (idx & 3) * 64, r0 = (idx >> 2) * 64;
    const int col4 = (tid & 15) * 4, rr0 = tid >> 4;
#pragma unroll
    for (int i = 0; i < 4; ++i) {
      int r = rr0 + i * 16;
      f32x4 v = *(const f32x4*)(wqkv + (size_t)(r0 + r) * 256 + c0 + col4);
      t[r][col4 + 0] = v[0]; t[r][col4 + 1] = v[1];
      t[r][col4 + 2] = v[2]; t[r][col4 + 3] = v[3];
    }
    __syncthreads();
    const int cc4 = (tid & 15) * 4, nr0 = tid >> 4;
#pragma unroll
    for (int i = 0; i < 4; ++i) {
      int nr = nr0 + i * 16;
      u16x4 u;
      u[0] = f2bf(t[cc4 + 0][nr]); u[1] = f2bf(t[cc4 + 1][nr]);
      u[2] = f2bf(t[cc4 + 2][nr]); u[3] = f2bf(t[cc4 + 3][nr]);
      *(u16x4*)(wqTb + (size_t)(c0 + nr) * 512 + r0 + cc4) = u;
    }
  }
}

// ---------------- fused kv + ctx (32-n chunks, 48KB LDS, 1 barrier/chunk) ----
// 512 threads = 8 waves: wq = wid&3 (32-row quarter of 128 kv rows),
// wn = wid>>2 (16-n half of the 32-n chunk). Per chunk c (32 chunks):
//   [__syncthreads]  (drains stage(c) vmem + ekv(c-1)/ctx(c-2) ds ops)
//   [stage(c+1) -> Bs[p^1]]          (Bs[p^1] readers kv(c-1) drained at bar)
//   [setprio; ctx(c-1) from ekv[p^1]; kv(c) from Bs[p]; setprio0]
//   [exp + cheap-RNE + write ekv[p]] (ekv[p] readers ctx(c-2) drained at bar)
__global__ __launch_bounds__(512, 4) void kv_ctx_fused(
    const u16* __restrict__ wkv,   // [1024][256] bf16 (k rows 0..511, v 512..1023)
    const u16* __restrict__ netT,  // [16][4096][256] bf16
    float* __restrict__ ctxp,      // [128][4][64][64]
    float* __restrict__ sump) {    // [128][4][64]
  __shared__ __align__(16) u16 Bs[2][8192];    // 32KB: [buf][32 n][256 c] swizzled
  __shared__ __align__(16) u16 ekL[2][2048];   // 8KB [buf][64 d][32 n] swizzled
  __shared__ __align__(16) u16 vL[2][2048];    // 8KB [buf][64 e][32 n] swizzled

  // XCD-aware decode: xcd = flat&7 hosts batches {2*xcd, 2*xcd+1} only.
  const int flat = blockIdx.x;
  const int xcd = flat & 7, inner = flat >> 3;
  const int b = 2 * xcd + (inner >> 5);
  const int h = (inner >> 2) & 7;
  const int s = inner & 3;

  const int tid = threadIdx.x, lane = tid & 63, wid = tid >> 6;
  const int wq = wid & 3, wn = wid >> 2;
  const int lr = lane & 15, lg = lane >> 4;
  const bool isK = (wq < 2);

  // ---- A-frags in registers: 32 rows x 256 K per wave (64 VGPR) ----
  bf16x8 af[2][8];
#pragma unroll
  for (int mi = 0; mi < 2; ++mi) {
    const int r = wq * 32 + mi * 16 + lr;                  // 0..127
    const int grow = (r < 64) ? h * 64 + r : 512 + h * 64 + (r - 64);
#pragma unroll
    for (int kk = 0; kk < 8; ++kk)
      af[mi][kk] = *(const bf16x8*)(wkv + (size_t)grow * 256 + kk * 32 + lg * 8);
  }

  const u16* Bsrc = netT + ((size_t)b * 4096 + s * 1024) * 256;
  const int srow = tid >> 5;       // 0..15 (+ i*16)
  const int sslot = tid & 31;      // 16B slot within row
  auto stage = [&](int c, int buf) {
    const u16* src = Bsrc + (size_t)c * 32 * 256;
#pragma unroll
    for (int i = 0; i < 2; ++i) {
      const int row = i * 16 + srow;
      const int scol = ((sslot ^ (row & 7)) * 8);
      async16(src + row * 256 + scol, &Bs[buf][i * 4096 + tid * 8]);
    }
  };

  f32x4 cacc[2] = {};          // ctx accum: d-group wq x e (wn*32 + ei*16)
  f32x4 sacc = {};             // rowsums (wn==0 waves only)
  bf16x8 ones8;
#pragma unroll
  for (int j = 0; j < 8; ++j) ((u16*)&ones8)[j] = 0x3F80;  // bf16 1.0

  // ctx accumulate from ekv buffer q (K = one 32-n chunk)
  auto ctx_acc = [&](int q) {
    const int d = wq * 16 + lr;
    bf16x8 ekf = *(const bf16x8*)&ekL[q][d * 32 + ((lg ^ (d & 3)) * 8)];
#pragma unroll
    for (int ei = 0; ei < 2; ++ei) {
      const int e = wn * 32 + ei * 16 + lr;
      bf16x8 vf = *(const bf16x8*)&vL[q][e * 32 + ((lg ^ (e & 3)) * 8)];
      cacc[ei] = __builtin_amdgcn_mfma_f32_16x16x32_bf16(ekf, vf, cacc[ei], 0, 0, 0);
    }
    if (wn == 0)
      sacc = __builtin_amdgcn_mfma_f32_16x16x32_bf16(ekf, ones8, sacc, 0, 0, 0);
  };

  stage(0, 0);
  const int nrow = wn * 16 + lr;

  for (int c = 0; c < 32; ++c) {
    const int p = c & 1;
    // single barrier: drains my stage(c) vmem (vmcnt 0) and all ds ops
    // (lgkmcnt 0) -> Bs[p] resident for all; ekv(c-1) visible; all reads of
    // Bs[p^1] (kv(c-1)) and ekv[p] (ctx(c-2)) completed block-wide.
    __syncthreads();
    if (c + 1 < 32) stage(c + 1, p ^ 1);   // safe: issued after the barrier

    // ---- merged MFMA region: ctx(c-1) + kv(c) ----
    f32x4 kvacc[2] = {};
    __builtin_amdgcn_s_setprio(1);
    if (c > 0) ctx_acc(p ^ 1);             // ekv written in iter c-1
#pragma unroll
    for (int kk = 0; kk < 8; ++kk) {
      bf16x8 bfr = *(const bf16x8*)&Bs[p][nrow * 256 + (((kk * 4 + lg) ^ (nrow & 7)) * 8)];
      kvacc[0] = __builtin_amdgcn_mfma_f32_16x16x32_bf16(af[0][kk], bfr, kvacc[0], 0, 0, 0);
      kvacc[1] = __builtin_amdgcn_mfma_f32_16x16x32_bf16(af[1][kk], bfr, kvacc[1], 0, 0, 0);
    }
    __builtin_amdgcn_s_setprio(0);

    // ---- exp (k-half) + cheap-RNE bf16 + write to swizzled ekv[p] ----
    u16* dstL = isK ? ekL[p] : vL[p];
#pragma unroll
    for (int mi = 0; mi < 2; ++mi)
#pragma unroll
      for (int j = 0; j < 4; ++j) {
        float v = kvacc[mi][j];
        if (isK) v = __expf(v);
        const u32 u = __float_as_uint(v);
        const u16 bv = (u16)((u + 0x8000u) >> 16);       // cheap RNE
        const int dd = (wq & 1) * 32 + mi * 16 + lg * 4 + j;   // 0..63
        dstL[dd * 32 + (((nrow >> 3) ^ (dd & 3)) * 8) + (nrow & 7)] = bv;
      }
  }
  __syncthreads();                 // ekv(31) visible
  ctx_acc(1);                      // ctx(31): buf 31&1 = 1

  // ---- store partials ----
  float* cp = ctxp + (((size_t)(b * 8 + h) * 4 + s) * 4096);
#pragma unroll
  for (int ei = 0; ei < 2; ++ei)
#pragma unroll
    for (int j = 0; j < 4; ++j) {
      const int d = wq * 16 + lg * 4 + j;
      const int e = wn * 32 + ei * 16 + lr;
      cp[d * 64 + e] = cacc[ei][j];
    }
  if (wn == 0 && lr == 0) {
#pragma unroll
    for (int j = 0; j < 4; ++j)
      sump[((size_t)(b * 8 + h) * 4 + s) * 64 + wq * 16 + lg * 4 + j] = sacc[j];
  }
}

// ---------------- fold_w2: reduce 4 partials, normalize, fold w_out ----------
__global__ __launch_bounds__(256) void fold_w2(const float* __restrict__ ctxp,
                                               const float* __restrict__ sump,
                                               const float* __restrict__ wout,
                                               u16* __restrict__ W2) {
  __shared__ float cl[16 * 64];
  __shared__ float sl[16];
  const int bh = blockIdx.x, dq = blockIdx.y;
  const int b = bh >> 3, h = bh & 7;
  const int tid = threadIdx.x;
  f32x4 v4 = {0.f, 0.f, 0.f, 0.f};
#pragma unroll
  for (int ch = 0; ch < 4; ++ch)
    v4 += *(const f32x4*)(ctxp + ((size_t)bh * 4 + ch) * 4096 + dq * 1024 + tid * 4);
  *(f32x4*)&cl[tid * 4] = v4;
  if (tid < 16) {
    float ss = 0.f;
#pragma unroll
    for (int ch = 0; ch < 4; ++ch)
      ss += sump[((size_t)bh * 4 + ch) * 64 + dq * 16 + tid];
    sl[tid] = ss;
  }
  __syncthreads();
  const int c = tid;
  f32x4 wv[16];
  const float* wrow = wout + (size_t)c * 512 + h * 64;
#pragma unroll
  for (int i = 0; i < 16; ++i) wv[i] = *(const f32x4*)(wrow + i * 4);
#pragma unroll
  for (int d = 0; d < 16; ++d) {
    f32x4 s4 = {0.f, 0.f, 0.f, 0.f};
#pragma unroll
    for (int e4 = 0; e4 < 16; ++e4) {
      f32x4 cv = *(const f32x4*)&cl[d * 64 + e4 * 4];
      s4 += wv[e4] * cv;
    }
    const float s = (s4[0] + s4[1] + s4[2] + s4[3]) / sl[d];
    W2[((size_t)b * 256 + c) * 512 + h * 64 + dq * 16 + d] = f2bf(s);
  }
}

// ---------------- gemm128: C[128x128] = A[128xK] * B[128xK]^T ----------------
// MODE 1: f32 out + bias; flat 1D grid with XCD-aware decode: both mt-blocks
//   of an (nt,b) land on one XCD 8-apart in dispatch order (netT L2-shared);
//   each XCD owns 2 batches (4MB netT = L2).
// MODE 2: bf16 plain (W3), standard 3D grid.
template <int LD, int NK, int MODE>
__global__ __launch_bounds__(256) void gemm128(const u16* __restrict__ A,
                                               const u16* __restrict__ B,
                                               size_t aStride, size_t bStride,
                                               void* __restrict__ O0,
                                               const float* __restrict__ bias) {
  __shared__ __align__(16) u16 SM[32768];
  int b, mt, nt;
  if constexpr (MODE == 1) {
    const int flat = blockIdx.x;
    const int xcd = flat & 7, r = flat >> 3;   // r 0..127
    b = 2 * xcd + (r >> 6);
    nt = (r & 63) >> 1;
    mt = r & 1;
  } else {
    b = blockIdx.z; mt = blockIdx.y; nt = blockIdx.x;
  }
  const int tid = threadIdx.x, lane = tid & 63, wid = tid >> 6;
  const int wr = wid >> 1, wc = wid & 1, lr = lane & 15, lg = lane >> 4;
  const u16* Ap = A + (size_t)b * aStride + (size_t)mt * 128 * LD;
  const u16* Bp = B + (size_t)b * bStride + (size_t)nt * 128 * LD;

  auto stage = [&](int buf, int ks) {
    const int k0 = ks * 64;
#pragma unroll
    for (int i = 0; i < 4; ++i) {
      const int idx = i * 2048 + tid * 8;
      const int r2 = idx >> 6, c2 = idx & 63;
      async16(Ap + (size_t)r2 * LD + k0 + c2, SM + buf * 8192 + i * 2048 + wid * 512);
      async16(Bp + (size_t)r2 * LD + k0 + c2, SM + 16384 + buf * 8192 + i * 2048 + wid * 512);
    }
  };

  f32x4 acc[4][4] = {};
  stage(0, 0);
  asm volatile("s_waitcnt vmcnt(0)" ::: "memory");
  __syncthreads();
  for (int ks = 0; ks < NK; ++ks) {
    const int buf = ks & 1;
    if (ks + 1 < NK) stage(buf ^ 1, ks + 1);
    const u16* Ab = SM + buf * 8192;
    const u16* Bb = SM + 16384 + buf * 8192;
#pragma unroll
    for (int kk = 0; kk < 2; ++kk) {
      bf16x8 afm[4], bfr[4];
#pragma unroll
      for (int mi = 0; mi < 4; ++mi)
        afm[mi] = *(const bf16x8*)(Ab + (wr * 64 + mi * 16 + lr) * 64 + kk * 32 + lg * 8);
#pragma unroll
      for (int ni = 0; ni < 4; ++ni)
        bfr[ni] = *(const bf16x8*)(Bb + (wc * 64 + ni * 16 + lr) * 64 + kk * 32 + lg * 8);
#pragma unroll
      for (int mi = 0; mi < 4; ++mi)
#pragma unroll
        for (int ni = 0; ni < 4; ++ni)
          acc[mi][ni] = __builtin_amdgcn_mfma_f32_16x16x32_bf16(afm[mi], bfr[ni], acc[mi][ni], 0, 0, 0);
    }
    asm volatile("s_waitcnt vmcnt(0)" ::: "memory");
    __syncthreads();
  }

  if constexpr (MODE == 2) {               // bf16 store (W3)
    u16* Cs = SM;
#pragma unroll
    for (int mi = 0; mi < 4; ++mi)
#pragma unroll
      for (int ni = 0; ni < 4; ++ni)
#pragma unroll
        for (int j = 0; j < 4; ++j)
          Cs[(wr * 64 + mi * 16 + lg * 4 + j) * 128 + wc * 64 + ni * 16 + lr] =
              f2bf(acc[mi][ni][j]);
    __syncthreads();
    u16* dst = (u16*)O0;
#pragma unroll
    for (int p = 0; p < 8; ++p) {
      const int idx = p * 2048 + tid * 8;
      const int r2 = idx >> 7, cc = idx & 127;
      *(u32x4*)(dst + ((size_t)b * 256 + mt * 128 + r2) * 256 + nt * 128 + cc) =
          *(const u32x4*)(Cs + idx);
    }
  } else {                                  // MODE 1: f32 + bias
    float* Cf = (float*)SM;                 // 64KB: 128x128 f32
#pragma unroll
    for (int mi = 0; mi < 4; ++mi)
#pragma unroll
      for (int ni = 0; ni < 4; ++ni)
#pragma unroll
        for (int j = 0; j < 4; ++j) {
          const int row = wr * 64 + mi * 16 + lg * 4 + j;
          Cf[row * 128 + wc * 64 + ni * 16 + lr] = acc[mi][ni][j] + bias[mt * 128 + row];
        }
    __syncthreads();
    float* op = (float*)O0;
#pragma unroll
    for (int p = 0; p < 16; ++p) {
      const int idx = p * 1024 + tid * 4;
      const int r2 = idx >> 7, cc = idx & 127;
      *(f32x4*)(op + ((size_t)b * 256 + mt * 128 + r2) * 4096 + nt * 128 + cc) =
          *(const f32x4*)(Cf + idx);
    }
  }
}

// ---------------------------------------------------------------------------
extern "C" void kernel_launch(void* const* d_in, const int* in_sizes, int n_in,
                              void* d_out, int out_size, void* d_ws, size_t ws_size,
                              hipStream_t stream) {
  const float* net  = (const float*)d_in[0];   // [16][256][4096]
  const float* wqkv = (const float*)d_in[1];   // [1536][256]
  const float* wout = (const float*)d_in[2];   // [256][512]
  const float* bout = (const float*)d_in[3];   // [256]
  float* out = (float*)d_out;

  char* ws = (char*)d_ws;
  u16*   netT = (u16*)(ws + 0);
  float* ctxp = (float*)(ws + 33554432);
  float* sump = (float*)(ws + 41943040);
  u16*   W2   = (u16*)(ws + 42074112);
  u16*   W3   = (u16*)(ws + 46268416);
  u16*   wkv  = (u16*)(ws + 48365568);
  u16*   wqTb = (u16*)(ws + 48889856);

  // net transpose + w_kv cast + w_q transpose in ONE launch
  prep_all<<<4384, 256, 0, stream>>>(net, netT, wqkv, wkv, wqTb);
  // fused kv + ctx (ek/vv never hit HBM); 512 blocks, 32 chunks, 1 bar/chunk
  kv_ctx_fused<<<512, 512, 0, stream>>>(wkv, netT, ctxp, sump);
  // reduce partials + normalize + fold with w_out
  fold_w2<<<dim3(128, 4), 256, 0, stream>>>(ctxp, sump, wout, W2);
  // W3[b] = W2[b] @ wqT : M=256 K=512 N=256
  gemm128<512, 8, 2><<<dim3(2, 2, 16), 256, 0, stream>>>(
      W2, wqTb, (size_t)256 * 512, 0, W3, nullptr);
  // out = W3 @ netT^T + b_out : M=256 K=256 N=4096 (flat XCD-aware grid)
  gemm128<256, 4, 1><<<dim3(1024, 1, 1), 256, 0, stream>>>(
      W3, netT, (size_t)256 * 256, (size_t)4096 * 256, out, bout);
}

// Round 18
// 106.338 us; speedup vs baseline: 1.1902x; 1.0065x over previous
//
#include <hip/hip_runtime.h>

// ---------------------------------------------------------------------------
// LinearDepthWiseAttention, round 18: r17 (107.0us best) + prep_all netT
// write-side vectorization: u16x4 (8B/lane) -> u16x8 (16B/lane) stores.
// Thread covers 8 consecutive c at one n-row; LDS reads audit to 2-way (free).
// All other kernels byte-identical to the thrice-verified configuration.
//   kv   = w_qkv[512:1536] @ net ; ek = exp(k)      (never hits HBM)
//   ctx[b,h] += ek_h @ v_h^T ; rowsums via all-ones B-frag MFMA
//   W2 = fold(w_out, ctx/sum) ; W3[b] = W2[b] @ w_q^T ; out = W3 @ net + b_out
// Workspace:
//   netT  [16][4096][256] bf16 @ 0          (33554432)
//   ctxp  [128][4][64][64] f32 @ 33554432   (8388608)
//   sump  [128][4][64]     f32 @ 41943040   (131072)
//   W2    [16][256][512]  bf16 @ 42074112   (4194304)
//   W3    [16][256][256]  bf16 @ 46268416   (2097152)
//   wkv   [1024][256]     bf16 @ 48365568   (524288)
//   wqTb  [256][512]      bf16 @ 48889856   (262144)
// ---------------------------------------------------------------------------

typedef unsigned short u16;
typedef unsigned int u32;
typedef __attribute__((ext_vector_type(4))) u16 u16x4;
typedef __attribute__((ext_vector_type(4))) u32 u32x4;
typedef __attribute__((ext_vector_type(4))) float f32x4;
typedef __attribute__((ext_vector_type(8))) short bf16x8;

__device__ __forceinline__ u16 f2bf(float f) {
  union { float f; u32 u; } x; x.f = f;
  u32 r = x.u + 0x7fffu + ((x.u >> 16) & 1u);   // round-to-nearest-even
  return (u16)(r >> 16);
}

// async global->LDS, 16B per lane; LDS dest must be wave-uniform base + lane*16.
__device__ __forceinline__ void async16(const u16* g, u16* l) {
  __builtin_amdgcn_global_load_lds(
      (const __attribute__((address_space(1))) void*)g,
      (__attribute__((address_space(3))) void*)l, 16, 0, 0);
}

// ---------------- prep_all: net transpose + weight prep, ONE launch ---------
// blocks 0..4095   : net transpose (b = blk>>8, c-tile = (blk>>6)&3, n-tile =
//                    blk&63); reads f32x4, writes u16x8 (16B/lane)
// blocks 4096..4351: w_kv cast (verbatim)
// blocks 4352..4383: w_q 64x64 transpose tile (verbatim)
__global__ __launch_bounds__(256) void prep_all(const float* __restrict__ net,
                                                u16* __restrict__ netT,
                                                const float* __restrict__ wqkv,
                                                u16* __restrict__ wkv,
                                                u16* __restrict__ wqTb) {
  __shared__ float t[64][65];
  const int blk = blockIdx.x;
  const int tid = threadIdx.x;
  if (blk < 4096) {                      // ---- net transpose (R=256,C=4096) ----
    const int b = blk >> 8, c0 = ((blk >> 6) & 3) * 64, n0 = (blk & 63) * 64;
    const float* ip = net + (size_t)b * 256 * 4096;
    u16* op = netT + (size_t)b * 256 * 4096;
    const int col4 = (tid & 15) * 4, rr0 = tid >> 4;
#pragma unroll
    for (int i = 0; i < 4; ++i) {
      int r = rr0 + i * 16;
      f32x4 v = *(const f32x4*)(ip + (size_t)(c0 + r) * 4096 + n0 + col4);
      t[r][col4 + 0] = v[0]; t[r][col4 + 1] = v[1];
      t[r][col4 + 2] = v[2]; t[r][col4 + 3] = v[3];
    }
    __syncthreads();
    // write phase: 16B/lane -- thread covers 8 consecutive c at one n-row
    const int c8 = (tid & 7) * 8, nr0 = tid >> 3;   // nr0 0..31
#pragma unroll
    for (int i = 0; i < 2; ++i) {
      int nr = nr0 + i * 32;
      u16 tmp[8];
#pragma unroll
      for (int k = 0; k < 8; ++k) tmp[k] = f2bf(t[c8 + k][nr]);
      *(u32x4*)(op + (size_t)(n0 + nr) * 256 + c0 + c8) = *(const u32x4*)tmp;
    }
  } else if (blk < 4352) {               // ---- w_kv cast ----
    const float* w = wqkv + 512 * 256;
    int i = ((blk - 4096) * 256 + tid) * 4;
    f32x4 v = *(const f32x4*)(w + i);
    u16x4 u;
    u[0] = f2bf(v[0]); u[1] = f2bf(v[1]); u[2] = f2bf(v[2]); u[3] = f2bf(v[3]);
    *(u16x4*)(wkv + i) = u;
  } else {                               // ---- w_q transpose (R=512,C=256) ----
    const int idx = blk - 4352;          // 0..31
    const int c0 = (idx & 3) * 64, r0 = (idx >> 2) * 64;
    const int col4 = (tid & 15) * 4, rr0 = tid >> 4;
#pragma unroll
    for (int i = 0; i < 4; ++i) {
      int r = rr0 + i * 16;
      f32x4 v = *(const f32x4*)(wqkv + (size_t)(r0 + r) * 256 + c0 + col4);
      t[r][col4 + 0] = v[0]; t[r][col4 + 1] = v[1];
      t[r][col4 + 2] = v[2]; t[r][col4 + 3] = v[3];
    }
    __syncthreads();
    const int cc4 = (tid & 15) * 4, nr0 = tid >> 4;
#pragma unroll
    for (int i = 0; i < 4; ++i) {
      int nr = nr0 + i * 16;
      u16x4 u;
      u[0] = f2bf(t[cc4 + 0][nr]); u[1] = f2bf(t[cc4 + 1][nr]);
      u[2] = f2bf(t[cc4 + 2][nr]); u[3] = f2bf(t[cc4 + 3][nr]);
      *(u16x4*)(wqTb + (size_t)(c0 + nr) * 512 + r0 + cc4) = u;
    }
  }
}

// ---------------- fused kv + ctx (32-n chunks, 48KB LDS, 1 barrier/chunk) ----
// 512 threads = 8 waves: wq = wid&3 (32-row quarter of 128 kv rows),
// wn = wid>>2 (16-n half of the 32-n chunk). Per chunk c (32 chunks):
//   [__syncthreads]  (drains stage(c) vmem + ekv(c-1)/ctx(c-2) ds ops)
//   [stage(c+1) -> Bs[p^1]]          (Bs[p^1] readers kv(c-1) drained at bar)
//   [setprio; ctx(c-1) from ekv[p^1]; kv(c) from Bs[p]; setprio0]
//   [exp + cheap-RNE + write ekv[p]] (ekv[p] readers ctx(c-2) drained at bar)
__global__ __launch_bounds__(512, 4) void kv_ctx_fused(
    const u16* __restrict__ wkv,   // [1024][256] bf16 (k rows 0..511, v 512..1023)
    const u16* __restrict__ netT,  // [16][4096][256] bf16
    float* __restrict__ ctxp,      // [128][4][64][64]
    float* __restrict__ sump) {    // [128][4][64]
  __shared__ __align__(16) u16 Bs[2][8192];    // 32KB: [buf][32 n][256 c] swizzled
  __shared__ __align__(16) u16 ekL[2][2048];   // 8KB [buf][64 d][32 n] swizzled
  __shared__ __align__(16) u16 vL[2][2048];    // 8KB [buf][64 e][32 n] swizzled

  // XCD-aware decode: xcd = flat&7 hosts batches {2*xcd, 2*xcd+1} only.
  const int flat = blockIdx.x;
  const int xcd = flat & 7, inner = flat >> 3;
  const int b = 2 * xcd + (inner >> 5);
  const int h = (inner >> 2) & 7;
  const int s = inner & 3;

  const int tid = threadIdx.x, lane = tid & 63, wid = tid >> 6;
  const int wq = wid & 3, wn = wid >> 2;
  const int lr = lane & 15, lg = lane >> 4;
  const bool isK = (wq < 2);

  // ---- A-frags in registers: 32 rows x 256 K per wave (64 VGPR) ----
  bf16x8 af[2][8];
#pragma unroll
  for (int mi = 0; mi < 2; ++mi) {
    const int r = wq * 32 + mi * 16 + lr;                  // 0..127
    const int grow = (r < 64) ? h * 64 + r : 512 + h * 64 + (r - 64);
#pragma unroll
    for (int kk = 0; kk < 8; ++kk)
      af[mi][kk] = *(const bf16x8*)(wkv + (size_t)grow * 256 + kk * 32 + lg * 8);
  }

  const u16* Bsrc = netT + ((size_t)b * 4096 + s * 1024) * 256;
  const int srow = tid >> 5;       // 0..15 (+ i*16)
  const int sslot = tid & 31;      // 16B slot within row
  auto stage = [&](int c, int buf) {
    const u16* src = Bsrc + (size_t)c * 32 * 256;
#pragma unroll
    for (int i = 0; i < 2; ++i) {
      const int row = i * 16 + srow;
      const int scol = ((sslot ^ (row & 7)) * 8);
      async16(src + row * 256 + scol, &Bs[buf][i * 4096 + tid * 8]);
    }
  };

  f32x4 cacc[2] = {};          // ctx accum: d-group wq x e (wn*32 + ei*16)
  f32x4 sacc = {};             // rowsums (wn==0 waves only)
  bf16x8 ones8;
#pragma unroll
  for (int j = 0; j < 8; ++j) ((u16*)&ones8)[j] = 0x3F80;  // bf16 1.0

  // ctx accumulate from ekv buffer q (K = one 32-n chunk)
  auto ctx_acc = [&](int q) {
    const int d = wq * 16 + lr;
    bf16x8 ekf = *(const bf16x8*)&ekL[q][d * 32 + ((lg ^ (d & 3)) * 8)];
#pragma unroll
    for (int ei = 0; ei < 2; ++ei) {
      const int e = wn * 32 + ei * 16 + lr;
      bf16x8 vf = *(const bf16x8*)&vL[q][e * 32 + ((lg ^ (e & 3)) * 8)];
      cacc[ei] = __builtin_amdgcn_mfma_f32_16x16x32_bf16(ekf, vf, cacc[ei], 0, 0, 0);
    }
    if (wn == 0)
      sacc = __builtin_amdgcn_mfma_f32_16x16x32_bf16(ekf, ones8, sacc, 0, 0, 0);
  };

  stage(0, 0);
  const int nrow = wn * 16 + lr;

  for (int c = 0; c < 32; ++c) {
    const int p = c & 1;
    // single barrier: drains my stage(c) vmem (vmcnt 0) and all ds ops
    // (lgkmcnt 0) -> Bs[p] resident for all; ekv(c-1) visible; all reads of
    // Bs[p^1] (kv(c-1)) and ekv[p] (ctx(c-2)) completed block-wide.
    __syncthreads();
    if (c + 1 < 32) stage(c + 1, p ^ 1);   // safe: issued after the barrier

    // ---- merged MFMA region: ctx(c-1) + kv(c) ----
    f32x4 kvacc[2] = {};
    __builtin_amdgcn_s_setprio(1);
    if (c > 0) ctx_acc(p ^ 1);             // ekv written in iter c-1
#pragma unroll
    for (int kk = 0; kk < 8; ++kk) {
      bf16x8 bfr = *(const bf16x8*)&Bs[p][nrow * 256 + (((kk * 4 + lg) ^ (nrow & 7)) * 8)];
      kvacc[0] = __builtin_amdgcn_mfma_f32_16x16x32_bf16(af[0][kk], bfr, kvacc[0], 0, 0, 0);
      kvacc[1] = __builtin_amdgcn_mfma_f32_16x16x32_bf16(af[1][kk], bfr, kvacc[1], 0, 0, 0);
    }
    __builtin_amdgcn_s_setprio(0);

    // ---- exp (k-half) + cheap-RNE bf16 + write to swizzled ekv[p] ----
    u16* dstL = isK ? ekL[p] : vL[p];
#pragma unroll
    for (int mi = 0; mi < 2; ++mi)
#pragma unroll
      for (int j = 0; j < 4; ++j) {
        float v = kvacc[mi][j];
        if (isK) v = __expf(v);
        const u32 u = __float_as_uint(v);
        const u16 bv = (u16)((u + 0x8000u) >> 16);       // cheap RNE
        const int dd = (wq & 1) * 32 + mi * 16 + lg * 4 + j;   // 0..63
        dstL[dd * 32 + (((nrow >> 3) ^ (dd & 3)) * 8) + (nrow & 7)] = bv;
      }
  }
  __syncthreads();                 // ekv(31) visible
  ctx_acc(1);                      // ctx(31): buf 31&1 = 1

  // ---- store partials ----
  float* cp = ctxp + (((size_t)(b * 8 + h) * 4 + s) * 4096);
#pragma unroll
  for (int ei = 0; ei < 2; ++ei)
#pragma unroll
    for (int j = 0; j < 4; ++j) {
      const int d = wq * 16 + lg * 4 + j;
      const int e = wn * 32 + ei * 16 + lr;
      cp[d * 64 + e] = cacc[ei][j];
    }
  if (wn == 0 && lr == 0) {
#pragma unroll
    for (int j = 0; j < 4; ++j)
      sump[((size_t)(b * 8 + h) * 4 + s) * 64 + wq * 16 + lg * 4 + j] = sacc[j];
  }
}

// ---------------- fold_w2: reduce 4 partials, normalize, fold w_out ----------
__global__ __launch_bounds__(256) void fold_w2(const float* __restrict__ ctxp,
                                               const float* __restrict__ sump,
                                               const float* __restrict__ wout,
                                               u16* __restrict__ W2) {
  __shared__ float cl[16 * 64];
  __shared__ float sl[16];
  const int bh = blockIdx.x, dq = blockIdx.y;
  const int b = bh >> 3, h = bh & 7;
  const int tid = threadIdx.x;
  f32x4 v4 = {0.f, 0.f, 0.f, 0.f};
#pragma unroll
  for (int ch = 0; ch < 4; ++ch)
    v4 += *(const f32x4*)(ctxp + ((size_t)bh * 4 + ch) * 4096 + dq * 1024 + tid * 4);
  *(f32x4*)&cl[tid * 4] = v4;
  if (tid < 16) {
    float ss = 0.f;
#pragma unroll
    for (int ch = 0; ch < 4; ++ch)
      ss += sump[((size_t)bh * 4 + ch) * 64 + dq * 16 + tid];
    sl[tid] = ss;
  }
  __syncthreads();
  const int c = tid;
  f32x4 wv[16];
  const float* wrow = wout + (size_t)c * 512 + h * 64;
#pragma unroll
  for (int i = 0; i < 16; ++i) wv[i] = *(const f32x4*)(wrow + i * 4);
#pragma unroll
  for (int d = 0; d < 16; ++d) {
    f32x4 s4 = {0.f, 0.f, 0.f, 0.f};
#pragma unroll
    for (int e4 = 0; e4 < 16; ++e4) {
      f32x4 cv = *(const f32x4*)&cl[d * 64 + e4 * 4];
      s4 += wv[e4] * cv;
    }
    const float s = (s4[0] + s4[1] + s4[2] + s4[3]) / sl[d];
    W2[((size_t)b * 256 + c) * 512 + h * 64 + dq * 16 + d] = f2bf(s);
  }
}

// ---------------- gemm128: C[128x128] = A[128xK] * B[128xK]^T ----------------
// MODE 1: f32 out + bias; flat 1D grid with XCD-aware decode: both mt-blocks
//   of an (nt,b) land on one XCD 8-apart in dispatch order (netT L2-shared);
//   each XCD owns 2 batches (4MB netT = L2).
// MODE 2: bf16 plain (W3), standard 3D grid.
template <int LD, int NK, int MODE>
__global__ __launch_bounds__(256) void gemm128(const u16* __restrict__ A,
                                               const u16* __restrict__ B,
                                               size_t aStride, size_t bStride,
                                               void* __restrict__ O0,
                                               const float* __restrict__ bias) {
  __shared__ __align__(16) u16 SM[32768];
  int b, mt, nt;
  if constexpr (MODE == 1) {
    const int flat = blockIdx.x;
    const int xcd = flat & 7, r = flat >> 3;   // r 0..127
    b = 2 * xcd + (r >> 6);
    nt = (r & 63) >> 1;
    mt = r & 1;
  } else {
    b = blockIdx.z; mt = blockIdx.y; nt = blockIdx.x;
  }
  const int tid = threadIdx.x, lane = tid & 63, wid = tid >> 6;
  const int wr = wid >> 1, wc = wid & 1, lr = lane & 15, lg = lane >> 4;
  const u16* Ap = A + (size_t)b * aStride + (size_t)mt * 128 * LD;
  const u16* Bp = B + (size_t)b * bStride + (size_t)nt * 128 * LD;

  auto stage = [&](int buf, int ks) {
    const int k0 = ks * 64;
#pragma unroll
    for (int i = 0; i < 4; ++i) {
      const int idx = i * 2048 + tid * 8;
      const int r2 = idx >> 6, c2 = idx & 63;
      async16(Ap + (size_t)r2 * LD + k0 + c2, SM + buf * 8192 + i * 2048 + wid * 512);
      async16(Bp + (size_t)r2 * LD + k0 + c2, SM + 16384 + buf * 8192 + i * 2048 + wid * 512);
    }
  };

  f32x4 acc[4][4] = {};
  stage(0, 0);
  asm volatile("s_waitcnt vmcnt(0)" ::: "memory");
  __syncthreads();
  for (int ks = 0; ks < NK; ++ks) {
    const int buf = ks & 1;
    if (ks + 1 < NK) stage(buf ^ 1, ks + 1);
    const u16* Ab = SM + buf * 8192;
    const u16* Bb = SM + 16384 + buf * 8192;
#pragma unroll
    for (int kk = 0; kk < 2; ++kk) {
      bf16x8 afm[4], bfr[4];
#pragma unroll
      for (int mi = 0; mi < 4; ++mi)
        afm[mi] = *(const bf16x8*)(Ab + (wr * 64 + mi * 16 + lr) * 64 + kk * 32 + lg * 8);
#pragma unroll
      for (int ni = 0; ni < 4; ++ni)
        bfr[ni] = *(const bf16x8*)(Bb + (wc * 64 + ni * 16 + lr) * 64 + kk * 32 + lg * 8);
#pragma unroll
      for (int mi = 0; mi < 4; ++mi)
#pragma unroll
        for (int ni = 0; ni < 4; ++ni)
          acc[mi][ni] = __builtin_amdgcn_mfma_f32_16x16x32_bf16(afm[mi], bfr[ni], acc[mi][ni], 0, 0, 0);
    }
    asm volatile("s_waitcnt vmcnt(0)" ::: "memory");
    __syncthreads();
  }

  if constexpr (MODE == 2) {               // bf16 store (W3)
    u16* Cs = SM;
#pragma unroll
    for (int mi = 0; mi < 4; ++mi)
#pragma unroll
      for (int ni = 0; ni < 4; ++ni)
#pragma unroll
        for (int j = 0; j < 4; ++j)
          Cs[(wr * 64 + mi * 16 + lg * 4 + j) * 128 + wc * 64 + ni * 16 + lr] =
              f2bf(acc[mi][ni][j]);
    __syncthreads();
    u16* dst = (u16*)O0;
#pragma unroll
    for (int p = 0; p < 8; ++p) {
      const int idx = p * 2048 + tid * 8;
      const int r2 = idx >> 7, cc = idx & 127;
      *(u32x4*)(dst + ((size_t)b * 256 + mt * 128 + r2) * 256 + nt * 128 + cc) =
          *(const u32x4*)(Cs + idx);
    }
  } else {                                  // MODE 1: f32 + bias
    float* Cf = (float*)SM;                 // 64KB: 128x128 f32
#pragma unroll
    for (int mi = 0; mi < 4; ++mi)
#pragma unroll
      for (int ni = 0; ni < 4; ++ni)
#pragma unroll
        for (int j = 0; j < 4; ++j) {
          const int row = wr * 64 + mi * 16 + lg * 4 + j;
          Cf[row * 128 + wc * 64 + ni * 16 + lr] = acc[mi][ni][j] + bias[mt * 128 + row];
        }
    __syncthreads();
    float* op = (float*)O0;
#pragma unroll
    for (int p = 0; p < 16; ++p) {
      const int idx = p * 1024 + tid * 4;
      const int r2 = idx >> 7, cc = idx & 127;
      *(f32x4*)(op + ((size_t)b * 256 + mt * 128 + r2) * 4096 + nt * 128 + cc) =
          *(const f32x4*)(Cf + idx);
    }
  }
}

// ---------------------------------------------------------------------------
extern "C" void kernel_launch(void* const* d_in, const int* in_sizes, int n_in,
                              void* d_out, int out_size, void* d_ws, size_t ws_size,
                              hipStream_t stream) {
  const float* net  = (const float*)d_in[0];   // [16][256][4096]
  const float* wqkv = (const float*)d_in[1];   // [1536][256]
  const float* wout = (const float*)d_in[2];   // [256][512]
  const float* bout = (const float*)d_in[3];   // [256]
  float* out = (float*)d_out;

  char* ws = (char*)d_ws;
  u16*   netT = (u16*)(ws + 0);
  float* ctxp = (float*)(ws + 33554432);
  float* sump = (float*)(ws + 41943040);
  u16*   W2   = (u16*)(ws + 42074112);
  u16*   W3   = (u16*)(ws + 46268416);
  u16*   wkv  = (u16*)(ws + 48365568);
  u16*   wqTb = (u16*)(ws + 48889856);

  // net transpose + w_kv cast + w_q transpose in ONE launch
  prep_all<<<4384, 256, 0, stream>>>(net, netT, wqkv, wkv, wqTb);
  // fused kv + ctx (ek/vv never hit HBM); 512 blocks, 32 chunks, 1 bar/chunk
  kv_ctx_fused<<<512, 512, 0, stream>>>(wkv, netT, ctxp, sump);
  // reduce partials + normalize + fold with w_out
  fold_w2<<<dim3(128, 4), 256, 0, stream>>>(ctxp, sump, wout, W2);
  // W3[b] = W2[b] @ wqT : M=256 K=512 N=256
  gemm128<512, 8, 2><<<dim3(2, 2, 16), 256, 0, stream>>>(
      W2, wqTb, (size_t)256 * 512, 0, W3, nullptr);
  // out = W3 @ netT^T + b_out : M=256 K=256 N=4096 (flat XCD-aware grid)
  gemm128<256, 4, 1><<<dim3(1024, 1, 1), 256, 0, stream>>>(
      W3, netT, (size_t)256 * 256, (size_t)4096 * 256, out, bout);
}